// Round 1
// baseline (9465.958 us; speedup 1.0000x reference)
//
#include <hip/hip_runtime.h>
#include <hip/hip_bf16.h>

// Causal transformer fwd: B=4 S=1024 H=1024 NH=16 DK=64 L=2 MLP=4x
// Round 0: correct fp32 baseline. GEMMs tiled 64x64 fp32; attention
// block-per-query-row with LDS scores; RoPE fused permute kernel.

#define B_ 4
#define S_ 1024
#define H_ 1024
#define NH_ 16
#define DK_ 64
#define MLPH_ 4096
#define EPS_ 1e-5f

__device__ __forceinline__ float gelu_tanh(float x) {
    float x3 = x * x * x;
    return 0.5f * x * (1.0f + tanhf(0.7978845608028654f * (x + 0.044715f * x3)));
}

// ---------------- LayerNorm: one block (256 thr) per row of 1024 ----------------
__global__ __launch_bounds__(256) void ln_kernel(const float* __restrict__ x,
                                                 const float* __restrict__ g,
                                                 const float* __restrict__ b,
                                                 float* __restrict__ y) {
    int row = blockIdx.x, tid = threadIdx.x;
    const float* xp = x + (size_t)row * H_;
    float4 v = *((const float4*)xp + tid);
    float s  = v.x + v.y + v.z + v.w;
    float s2 = v.x * v.x + v.y * v.y + v.z * v.z + v.w * v.w;
    #pragma unroll
    for (int o = 1; o < 64; o <<= 1) {
        s  += __shfl_xor(s, o, 64);
        s2 += __shfl_xor(s2, o, 64);
    }
    __shared__ float r1[4], r2[4];
    if ((tid & 63) == 0) { r1[tid >> 6] = s; r2[tid >> 6] = s2; }
    __syncthreads();
    s  = r1[0] + r1[1] + r1[2] + r1[3];
    s2 = r2[0] + r2[1] + r2[2] + r2[3];
    float mean = s * (1.0f / H_);
    float var  = s2 * (1.0f / H_) - mean * mean;
    float inv  = rsqrtf(var + EPS_);
    float4 gv = *((const float4*)g + tid);
    float4 bv = *((const float4*)b + tid);
    float4 o;
    o.x = (v.x - mean) * inv * gv.x + bv.x;
    o.y = (v.y - mean) * inv * gv.y + bv.y;
    o.z = (v.z - mean) * inv * gv.z + bv.z;
    o.w = (v.w - mean) * inv * gv.w + bv.w;
    *((float4*)(y + (size_t)row * H_) + tid) = o;
}

// ---------------- Tiled fp32 GEMM: C = act(A@W + bias [+ resid]) ----------------
// A:[M,K] row-major, W:[K,N] row-major. 64x64 tile, BK=16, 256 thr, 4x4 per thr.
__global__ __launch_bounds__(256) void gemm_f32(const float* __restrict__ A,
                                                const float* __restrict__ W,
                                                const float* __restrict__ bias,
                                                const float* __restrict__ resid,
                                                float* __restrict__ C,
                                                int M, int N, int K, int act) {
    __shared__ float As[16][64];
    __shared__ float Bs[16][64];
    int tid = threadIdx.x;
    int tx = tid & 15, ty = tid >> 4;
    int row0 = blockIdx.y * 64, col0 = blockIdx.x * 64;
    int a_r = tid >> 2, a_k = (tid & 3) * 4;
    int b_k = tid >> 4, b_c = (tid & 15) * 4;
    const float* Ap = A + (size_t)(row0 + a_r) * K + a_k;
    const float* Wp = W + (size_t)b_k * N + col0 + b_c;
    float c[4][4] = {};
    for (int k0 = 0; k0 < K; k0 += 16) {
        float4 av = *(const float4*)(Ap + k0);
        float4 wv = *(const float4*)(Wp + (size_t)k0 * N);
        __syncthreads();
        As[a_k + 0][a_r] = av.x;
        As[a_k + 1][a_r] = av.y;
        As[a_k + 2][a_r] = av.z;
        As[a_k + 3][a_r] = av.w;
        *(float4*)&Bs[b_k][b_c] = wv;
        __syncthreads();
        #pragma unroll
        for (int kk = 0; kk < 16; kk++) {
            float4 a = *(const float4*)&As[kk][ty * 4];
            float4 b = *(const float4*)&Bs[kk][tx * 4];
            c[0][0] += a.x * b.x; c[0][1] += a.x * b.y; c[0][2] += a.x * b.z; c[0][3] += a.x * b.w;
            c[1][0] += a.y * b.x; c[1][1] += a.y * b.y; c[1][2] += a.y * b.z; c[1][3] += a.y * b.w;
            c[2][0] += a.z * b.x; c[2][1] += a.z * b.y; c[2][2] += a.z * b.z; c[2][3] += a.z * b.w;
            c[3][0] += a.w * b.x; c[3][1] += a.w * b.y; c[3][2] += a.w * b.z; c[3][3] += a.w * b.w;
        }
    }
    int row = row0 + ty * 4, col = col0 + tx * 4;
    float4 bv = *(const float4*)(bias + col);
    #pragma unroll
    for (int i = 0; i < 4; i++) {
        float4 v;
        v.x = c[i][0] + bv.x; v.y = c[i][1] + bv.y;
        v.z = c[i][2] + bv.z; v.w = c[i][3] + bv.w;
        if (resid) {
            float4 r = *(const float4*)(resid + (size_t)(row + i) * N + col);
            v.x += r.x; v.y += r.y; v.z += r.z; v.w += r.w;
        }
        if (act == 1) {
            v.x = gelu_tanh(v.x); v.y = gelu_tanh(v.y);
            v.z = gelu_tanh(v.z); v.w = gelu_tanh(v.w);
        }
        *(float4*)(C + (size_t)(row + i) * N + col) = v;
    }
}

// ---------------- RoPE + split heads: qkv[B,S,3H] -> q/k/v [B,NH,S,DK] ----------------
__global__ __launch_bounds__(256) void rope_kernel(const float* __restrict__ qkv,
                                                   const int* __restrict__ pos,
                                                   float* __restrict__ qt,
                                                   float* __restrict__ kt,
                                                   float* __restrict__ vt) {
    int idx = blockIdx.x * 256 + threadIdx.x;  // (((b*NH+h)*S+s)*DK+d)
    int d = idx & 63;
    int s = (idx >> 6) & 1023;
    int h = (idx >> 16) & 15;
    int b = idx >> 20;
    size_t base = ((size_t)(b * S_ + s)) * (3 * H_);
    int c0 = h * DK_ + d;
    float q = qkv[base + c0];
    float k = qkv[base + H_ + c0];
    float v = qkv[base + 2 * H_ + c0];
    int d2 = d & 31;
    int cp = h * DK_ + ((d < 32) ? (d + 32) : (d - 32));
    float qp = qkv[base + cp];
    float kp = qkv[base + H_ + cp];
    float rq = (d < 32) ? -qp : qp;
    float rk = (d < 32) ? -kp : kp;
    float p = (float)pos[s];
    float inv_freq = expf(-9.210340371976184f * ((float)d2 / 32.0f));  // 10000^(-2*d2/64)
    float th = p * inv_freq;
    float cs = cosf(th), sn = sinf(th);
    qt[idx] = q * cs + rq * sn;
    kt[idx] = k * cs + rk * sn;
    vt[idx] = v;
}

// ---------------- Attention: one block per (b,h,q). Scores in LDS, causal. ----------------
__global__ __launch_bounds__(256) void attn_kernel(const float* __restrict__ Q,
                                                   const float* __restrict__ K,
                                                   const float* __restrict__ V,
                                                   float* __restrict__ Out) {
    int q = blockIdx.x, h = blockIdx.y, b = blockIdx.z;
    int tid = threadIdx.x;
    __shared__ float sc[S_];
    __shared__ float qs[DK_];
    __shared__ float red[4];
    __shared__ float pacc[4][DK_];
    const float* Qp = Q + (((size_t)b * NH_ + h) * S_ + q) * DK_;
    const float* Kp = K + ((size_t)b * NH_ + h) * S_ * DK_;
    const float* Vp = V + ((size_t)b * NH_ + h) * S_ * DK_;
    if (tid < DK_) qs[tid] = Qp[tid];
    __syncthreads();
    int n = q + 1;
    const float scale = 0.125f;  // 1/sqrt(64)
    for (int j = tid; j < n; j += 256) {
        const float4* kr = (const float4*)(Kp + (size_t)j * DK_);
        const float4* qr = (const float4*)qs;
        float acc = 0.0f;
        #pragma unroll
        for (int t = 0; t < 16; t++) {
            float4 kv = kr[t], qv = qr[t];
            acc += qv.x * kv.x + qv.y * kv.y + qv.z * kv.z + qv.w * kv.w;
        }
        sc[j] = acc * scale;
    }
    __syncthreads();
    // max
    float m = -3.0e38f;
    for (int j = tid; j < n; j += 256) m = fmaxf(m, sc[j]);
    #pragma unroll
    for (int o = 1; o < 64; o <<= 1) m = fmaxf(m, __shfl_xor(m, o, 64));
    if ((tid & 63) == 0) red[tid >> 6] = m;
    __syncthreads();
    m = fmaxf(fmaxf(red[0], red[1]), fmaxf(red[2], red[3]));
    __syncthreads();
    // exp + sum
    float s = 0.0f;
    for (int j = tid; j < n; j += 256) {
        float e = expf(sc[j] - m);
        sc[j] = e;
        s += e;
    }
    #pragma unroll
    for (int o = 1; o < 64; o <<= 1) s += __shfl_xor(s, o, 64);
    if ((tid & 63) == 0) red[tid >> 6] = s;
    __syncthreads();
    s = red[0] + red[1] + red[2] + red[3];
    float inv = 1.0f / s;
    // PV: 4 partials x 64 dims
    int d = tid & 63, part = tid >> 6;
    float acc = 0.0f;
    for (int j = part; j < n; j += 4) acc += sc[j] * Vp[(size_t)j * DK_ + d];
    pacc[part][d] = acc;
    __syncthreads();
    if (tid < DK_) {
        float o = (pacc[0][tid] + pacc[1][tid] + pacc[2][tid] + pacc[3][tid]) * inv;
        Out[((size_t)(b * S_ + q)) * H_ + h * DK_ + tid] = o;
    }
}

extern "C" void kernel_launch(void* const* d_in, const int* in_sizes, int n_in,
                              void* d_out, int out_size, void* d_ws, size_t ws_size,
                              hipStream_t stream) {
    const float* hs     = (const float*)d_in[0];
    const float* attn_w = (const float*)d_in[1];
    const float* attn_b = (const float*)d_in[2];
    const float* proj_w = (const float*)d_in[3];
    const float* proj_b = (const float*)d_in[4];
    const float* fc_w   = (const float*)d_in[5];
    const float* fc_b   = (const float*)d_in[6];
    const float* fc2_w  = (const float*)d_in[7];
    const float* fc2_b  = (const float*)d_in[8];
    const float* ln1_g  = (const float*)d_in[9];
    const float* ln1_b  = (const float*)d_in[10];
    const float* ln2_g  = (const float*)d_in[11];
    const float* ln2_b  = (const float*)d_in[12];
    const int*   pos    = (const int*)d_in[13];

    float* h = (float*)d_out;  // running residual [B*S, H]

    const size_t rows = (size_t)B_ * S_;            // 4096
    float* buf_x   = (float*)d_ws;                  // [4096,1024]
    float* buf_big = buf_x + rows * H_;             // [4096,4096] (qkv uses 3072 cols)
    float* qt      = buf_big + rows * MLPH_;        // [B,NH,S,DK]
    float* kt      = qt + rows * H_;
    float* vt      = kt + rows * H_;

    hipMemcpyAsync(h, hs, rows * H_ * sizeof(float), hipMemcpyDeviceToDevice, stream);

    const int nelem_heads = B_ * NH_ * S_ * DK_;  // 4194304

    for (int l = 0; l < 2; l++) {
        // x = LN1(h)
        ln_kernel<<<rows, 256, 0, stream>>>(h, ln1_g + l * H_, ln1_b + l * H_, buf_x);
        // qkv = x @ attn_w + attn_b   [4096, 3072]
        gemm_f32<<<dim3(3 * H_ / 64, rows / 64), 256, 0, stream>>>(
            buf_x, attn_w + (size_t)l * H_ * 3 * H_, attn_b + (size_t)l * 3 * H_,
            nullptr, buf_big, rows, 3 * H_, H_, 0);
        // rope + split heads
        rope_kernel<<<nelem_heads / 256, 256, 0, stream>>>(buf_big, pos, qt, kt, vt);
        // attention -> buf_x (merged heads [B,S,H])
        attn_kernel<<<dim3(S_, NH_, B_), 256, 0, stream>>>(qt, kt, vt, buf_x);
        // h = h + buf_x @ proj_w + proj_b
        gemm_f32<<<dim3(H_ / 64, rows / 64), 256, 0, stream>>>(
            buf_x, proj_w + (size_t)l * H_ * H_, proj_b + (size_t)l * H_,
            h, h, rows, H_, H_, 0);
        // x = LN2(h)
        ln_kernel<<<rows, 256, 0, stream>>>(h, ln2_g + l * H_, ln2_b + l * H_, buf_x);
        // mid = gelu(x @ fc_w + fc_b)  [4096, 4096]
        gemm_f32<<<dim3(MLPH_ / 64, rows / 64), 256, 0, stream>>>(
            buf_x, fc_w + (size_t)l * H_ * MLPH_, fc_b + (size_t)l * MLPH_,
            nullptr, buf_big, rows, MLPH_, H_, 1);
        // h = h + mid @ fc2_w + fc2_b
        gemm_f32<<<dim3(H_ / 64, rows / 64), 256, 0, stream>>>(
            buf_big, fc2_w + (size_t)l * MLPH_ * H_, fc2_b + (size_t)l * H_,
            h, h, rows, H_, MLPH_, 0);
    }
}

// Round 2
// 1032.025 us; speedup vs baseline: 9.1722x; 9.1722x over previous
//
#include <hip/hip_runtime.h>

#define B_ 4
#define S_ 1024
#define H_ 1024
#define NH_ 16
#define DK_ 64
#define MLPH_ 4096
#define EPS_ 1e-5f

typedef __attribute__((ext_vector_type(8))) short short8_t;
typedef __attribute__((ext_vector_type(8))) unsigned short ushort8_t;
typedef __attribute__((ext_vector_type(4))) float f32x4;

__device__ __forceinline__ unsigned short f2bf(float f) {
  unsigned int u = __float_as_uint(f);
  u = u + 0x7fffu + ((u >> 16) & 1u);  // RNE
  return (unsigned short)(u >> 16);
}
__device__ __forceinline__ float bf2f(unsigned short b) {
  return __uint_as_float(((unsigned int)b) << 16);
}

__device__ __forceinline__ void gload16(const void* g, void* l) {
  typedef const __attribute__((address_space(1))) unsigned int GU;
  typedef __attribute__((address_space(3))) unsigned int LU;
  __builtin_amdgcn_global_load_lds((GU*)(size_t)g, (LU*)(unsigned int)(size_t)l, 16, 0, 0);
}

__device__ __forceinline__ float gelu_tanh(float x) {
  float x3 = x * x * x;
  return 0.5f * x * (1.0f + tanhf(0.7978845608028654f * (x + 0.044715f * x3)));
}

// ---------------- weight fp32 [K,N] -> bf16 [N,K] transpose ----------------
__global__ __launch_bounds__(256) void wconv(const float* __restrict__ src,
                                             unsigned short* __restrict__ dst,
                                             int K, int N) {
  __shared__ float t[32][33];
  int n0 = blockIdx.x * 32, k0 = blockIdx.y * 32;
  int tid = threadIdx.x;
  int r = tid >> 3, c = (tid & 7) * 4;
  const float* s = src + (size_t)(k0 + r) * N + n0 + c;
  float4 v = *(const float4*)s;
  t[r][c] = v.x; t[r][c + 1] = v.y; t[r][c + 2] = v.z; t[r][c + 3] = v.w;
  __syncthreads();
  ushort4 o;
  o.x = f2bf(t[c + 0][r]); o.y = f2bf(t[c + 1][r]);
  o.z = f2bf(t[c + 2][r]); o.w = f2bf(t[c + 3][r]);
  *(ushort4*)(dst + (size_t)(n0 + r) * K + k0 + c) = o;
}

// ---------------- LayerNorm -> bf16 out ----------------
__global__ __launch_bounds__(256) void ln_kernel(const float* __restrict__ x,
                                                 const float* __restrict__ g,
                                                 const float* __restrict__ b,
                                                 unsigned short* __restrict__ y) {
  int row = blockIdx.x, tid = threadIdx.x;
  const float* xp = x + (size_t)row * H_;
  float4 v = *((const float4*)xp + tid);
  float s  = v.x + v.y + v.z + v.w;
  float s2 = v.x * v.x + v.y * v.y + v.z * v.z + v.w * v.w;
  #pragma unroll
  for (int o = 1; o < 64; o <<= 1) {
    s  += __shfl_xor(s, o, 64);
    s2 += __shfl_xor(s2, o, 64);
  }
  __shared__ float r1[4], r2[4];
  if ((tid & 63) == 0) { r1[tid >> 6] = s; r2[tid >> 6] = s2; }
  __syncthreads();
  s  = r1[0] + r1[1] + r1[2] + r1[3];
  s2 = r2[0] + r2[1] + r2[2] + r2[3];
  float mean = s * (1.0f / H_);
  float var  = s2 * (1.0f / H_) - mean * mean;
  float inv  = rsqrtf(var + EPS_);
  float4 gv = *((const float4*)g + tid);
  float4 bv = *((const float4*)b + tid);
  ushort4 o;
  o.x = f2bf((v.x - mean) * inv * gv.x + bv.x);
  o.y = f2bf((v.y - mean) * inv * gv.y + bv.y);
  o.z = f2bf((v.z - mean) * inv * gv.z + bv.z);
  o.w = f2bf((v.w - mean) * inv * gv.w + bv.w);
  *(ushort4*)(y + (size_t)row * H_ + tid * 4) = o;
}

// ---------------- RoPE in-place on qkv bf16 [B,S,3H] ----------------
__global__ __launch_bounds__(256) void rope_bf(unsigned short* qkv, const int* __restrict__ pos) {
  int idx = blockIdx.x * 256 + threadIdx.x;  // over B*S*NH*32
  int d = idx & 31;
  int hh = (idx >> 5) & 15;
  int s = (idx >> 9) & 1023;
  int b = idx >> 19;
  size_t base = ((size_t)(b * S_ + s)) * 3072 + hh * 64;
  float inv = __expf(-9.210340371976184f * ((float)d * 0.03125f));  // 10000^(-d/32)
  float th = (float)pos[s] * inv;
  float cs = cosf(th), sn = sinf(th);
  unsigned short* qp = qkv + base;
  unsigned short* kp = qkv + base + 1024;
  float q0 = bf2f(qp[d]), q1 = bf2f(qp[d + 32]);
  float k0 = bf2f(kp[d]), k1 = bf2f(kp[d + 32]);
  qp[d]      = f2bf(q0 * cs - q1 * sn);
  qp[d + 32] = f2bf(q1 * cs + q0 * sn);
  kp[d]      = f2bf(k0 * cs - k1 * sn);
  kp[d + 32] = f2bf(k1 * cs + k0 * sn);
}

// ---------------- bf16 MFMA GEMM: 128x128 tile, BK=32, 4 waves ----------------
// A:[M,K] bf16 row-major; Bt:[N,K] bf16 row-major (W^T).
// MODE 0: out bf16 = A*W + bias; MODE 1: out bf16 = gelu(...); MODE 2: out f32 = resid + ...
template <int MODE>
__global__ __launch_bounds__(256) void gemm_mfma(
    const unsigned short* __restrict__ A, const unsigned short* __restrict__ Bt,
    const float* __restrict__ bias, const float* __restrict__ resid,
    void* __restrict__ outp, int M, int N, int K) {
  __shared__ __align__(16) unsigned short As[128 * 32];
  __shared__ __align__(16) unsigned short Bs[128 * 32];
  int tid = threadIdx.x;
  int w = tid >> 6, lane = tid & 63;
  int m0 = blockIdx.y * 128, n0 = blockIdx.x * 128;
  int wr = w >> 1, wc = w & 1;
  f32x4 acc[4][4];
  #pragma unroll
  for (int m = 0; m < 4; m++)
    #pragma unroll
    for (int n = 0; n < 4; n++) {
      acc[m][n][0] = 0.f; acc[m][n][1] = 0.f; acc[m][n][2] = 0.f; acc[m][n][3] = 0.f;
    }
  int arow = lane >> 2, acol = (lane & 3) * 8;
  int c0 = w * 2, c1 = w * 2 + 1;
  const unsigned short* A0 = A + (size_t)(m0 + c0 * 16 + arow) * K + acol;
  const unsigned short* A1 = A + (size_t)(m0 + c1 * 16 + arow) * K + acol;
  const unsigned short* B0 = Bt + (size_t)(n0 + c0 * 16 + arow) * K + acol;
  const unsigned short* B1 = Bt + (size_t)(n0 + c1 * 16 + arow) * K + acol;
  int fr = lane & 15, krow = (lane >> 4) * 8;
  for (int k0 = 0; k0 < K; k0 += 32) {
    __syncthreads();
    gload16(A0 + k0, (char*)As + c0 * 1024);
    gload16(A1 + k0, (char*)As + c1 * 1024);
    gload16(B0 + k0, (char*)Bs + c0 * 1024);
    gload16(B1 + k0, (char*)Bs + c1 * 1024);
    __syncthreads();
    short8_t af[4], bfr[4];
    #pragma unroll
    for (int m = 0; m < 4; m++)
      af[m] = *(const short8_t*)&As[(wr * 64 + m * 16 + fr) * 32 + krow];
    #pragma unroll
    for (int n = 0; n < 4; n++)
      bfr[n] = *(const short8_t*)&Bs[(wc * 64 + n * 16 + fr) * 32 + krow];
    #pragma unroll
    for (int m = 0; m < 4; m++)
      #pragma unroll
      for (int n = 0; n < 4; n++)
        acc[m][n] = __builtin_amdgcn_mfma_f32_16x16x32_bf16(af[m], bfr[n], acc[m][n], 0, 0, 0);
  }
  int orow = (lane >> 4) * 4;
  #pragma unroll
  for (int n = 0; n < 4; n++) {
    int col = n0 + wc * 64 + n * 16 + fr;
    float bv = bias[col];
    #pragma unroll
    for (int m = 0; m < 4; m++) {
      int row = m0 + wr * 64 + m * 16 + orow;
      #pragma unroll
      for (int r = 0; r < 4; r++) {
        float v = acc[m][n][r] + bv;
        size_t idx = (size_t)(row + r) * N + col;
        if (MODE == 2)      ((float*)outp)[idx] = resid[idx] + v;
        else if (MODE == 1) ((unsigned short*)outp)[idx] = f2bf(gelu_tanh(v));
        else                ((unsigned short*)outp)[idx] = f2bf(v);
      }
    }
  }
}

// ---------------- Attention: 64-row q-tile per block, online softmax ----------------
__global__ __launch_bounds__(256) void attn2(const unsigned short* __restrict__ qkv,
                                             unsigned short* __restrict__ aout) {
  __shared__ __align__(16) float QsT[64][68];  // [k][m]
  __shared__ __align__(16) float KsT[64][68];  // [k][n]
  __shared__ __align__(16) float Vs[64][68];   // [j][d]
  __shared__ __align__(16) float Ps[64][68];   // [n][m]
  int tid = threadIdx.x;
  int q0 = blockIdx.x * 64;
  int head = blockIdx.y;
  int b = blockIdx.z;
  int m = tid & 63, cg = (tid >> 6) * 16;
  int tx = tid & 15, ty = tid >> 4;
  const unsigned short* base = qkv + (size_t)b * S_ * 3072 + head * 64;
  {
    const unsigned short* qp = base + (size_t)(q0 + m) * 3072 + cg;
    ushort8_t u0 = *(const ushort8_t*)qp;
    ushort8_t u1 = *(const ushort8_t*)(qp + 8);
    #pragma unroll
    for (int i = 0; i < 8; i++) { QsT[cg + i][m] = bf2f(u0[i]); QsT[cg + 8 + i][m] = bf2f(u1[i]); }
  }
  float acc[4][4];
  float mrun[4], lrun[4];
  #pragma unroll
  for (int i = 0; i < 4; i++) {
    mrun[i] = -3.0e38f; lrun[i] = 0.f;
    acc[i][0] = acc[i][1] = acc[i][2] = acc[i][3] = 0.f;
  }
  int ntile = q0 / 64 + 1;
  for (int t = 0; t < ntile; t++) {
    __syncthreads();
    {
      const unsigned short* kp = base + 1024 + (size_t)(t * 64 + m) * 3072 + cg;
      const unsigned short* vp = base + 2048 + (size_t)(t * 64 + m) * 3072 + cg;
      ushort8_t k0v = *(const ushort8_t*)kp;
      ushort8_t k1v = *(const ushort8_t*)(kp + 8);
      ushort8_t v0v = *(const ushort8_t*)vp;
      ushort8_t v1v = *(const ushort8_t*)(vp + 8);
      #pragma unroll
      for (int i = 0; i < 8; i++) { KsT[cg + i][m] = bf2f(k0v[i]); KsT[cg + 8 + i][m] = bf2f(k1v[i]); }
      #pragma unroll
      for (int i = 0; i < 8; i++) { Vs[m][cg + i] = bf2f(v0v[i]); Vs[m][cg + 8 + i] = bf2f(v1v[i]); }
    }
    __syncthreads();
    float c[4][4];
    #pragma unroll
    for (int i = 0; i < 4; i++) c[i][0] = c[i][1] = c[i][2] = c[i][3] = 0.f;
    #pragma unroll 4
    for (int k = 0; k < 64; k++) {
      f32x4 qv = *(const f32x4*)&QsT[k][ty * 4];
      f32x4 kv = *(const f32x4*)&KsT[k][tx * 4];
      #pragma unroll
      for (int i = 0; i < 4; i++)
        #pragma unroll
        for (int j = 0; j < 4; j++) c[i][j] += qv[i] * kv[j];
    }
    int qrow = q0 + ty * 4;
    int kcol = t * 64 + tx * 4;
    #pragma unroll
    for (int i = 0; i < 4; i++)
      #pragma unroll
      for (int j = 0; j < 4; j++) {
        float sv = c[i][j] * 0.125f;
        c[i][j] = (kcol + j > qrow + i) ? -1.0e30f : sv;
      }
    float p[4][4];
    #pragma unroll
    for (int i = 0; i < 4; i++) {
      float tm = fmaxf(fmaxf(c[i][0], c[i][1]), fmaxf(c[i][2], c[i][3]));
      tm = fmaxf(tm, __shfl_xor(tm, 1, 64));
      tm = fmaxf(tm, __shfl_xor(tm, 2, 64));
      tm = fmaxf(tm, __shfl_xor(tm, 4, 64));
      tm = fmaxf(tm, __shfl_xor(tm, 8, 64));
      float mn = fmaxf(mrun[i], tm);
      float sc = __expf(mrun[i] - mn);
      mrun[i] = mn;
      float ls = 0.f;
      #pragma unroll
      for (int j = 0; j < 4; j++) { p[i][j] = __expf(c[i][j] - mn); ls += p[i][j]; }
      ls += __shfl_xor(ls, 1, 64);
      ls += __shfl_xor(ls, 2, 64);
      ls += __shfl_xor(ls, 4, 64);
      ls += __shfl_xor(ls, 8, 64);
      lrun[i] = lrun[i] * sc + ls;
      acc[i][0] *= sc; acc[i][1] *= sc; acc[i][2] *= sc; acc[i][3] *= sc;
    }
    #pragma unroll
    for (int j = 0; j < 4; j++)
      #pragma unroll
      for (int i = 0; i < 4; i++)
        Ps[tx * 4 + j][ty * 4 + i] = p[i][j];
    __syncthreads();
    #pragma unroll 4
    for (int j = 0; j < 64; j++) {
      f32x4 pv = *(const f32x4*)&Ps[j][ty * 4];
      f32x4 vv = *(const f32x4*)&Vs[j][tx * 4];
      #pragma unroll
      for (int i = 0; i < 4; i++)
        #pragma unroll
        for (int d = 0; d < 4; d++) acc[i][d] += pv[i] * vv[d];
    }
  }
  #pragma unroll
  for (int i = 0; i < 4; i++) {
    float inv = 1.0f / lrun[i];
    ushort4 o;
    o.x = f2bf(acc[i][0] * inv);
    o.y = f2bf(acc[i][1] * inv);
    o.z = f2bf(acc[i][2] * inv);
    o.w = f2bf(acc[i][3] * inv);
    *(ushort4*)(aout + ((size_t)b * S_ + q0 + ty * 4 + i) * H_ + head * 64 + tx * 4) = o;
  }
}

extern "C" void kernel_launch(void* const* d_in, const int* in_sizes, int n_in,
                              void* d_out, int out_size, void* d_ws, size_t ws_size,
                              hipStream_t stream) {
  const float* hs     = (const float*)d_in[0];
  const float* attn_w = (const float*)d_in[1];
  const float* attn_b = (const float*)d_in[2];
  const float* proj_w = (const float*)d_in[3];
  const float* proj_b = (const float*)d_in[4];
  const float* fc_w   = (const float*)d_in[5];
  const float* fc_b   = (const float*)d_in[6];
  const float* fc2_w  = (const float*)d_in[7];
  const float* fc2_b  = (const float*)d_in[8];
  const float* ln1_g  = (const float*)d_in[9];
  const float* ln1_b  = (const float*)d_in[10];
  const float* ln2_g  = (const float*)d_in[11];
  const float* ln2_b  = (const float*)d_in[12];
  const int*   pos    = (const int*)d_in[13];

  float* hres = (float*)d_out;
  const size_t rows = (size_t)B_ * S_;  // 4096

  unsigned short* wQ    = (unsigned short*)d_ws;          // [L][3072][1024]
  unsigned short* wP    = wQ  + (size_t)2 * 3072 * 1024;  // [L][1024][1024]
  unsigned short* wF1   = wP  + (size_t)2 * 1024 * 1024;  // [L][4096][1024]
  unsigned short* wF2   = wF1 + (size_t)2 * 4096 * 1024;  // [L][1024][4096]
  unsigned short* xbf   = wF2 + (size_t)2 * 1024 * 4096;  // [4096][1024]
  unsigned short* qkvbf = xbf + rows * H_;                // [4096][3072]
  unsigned short* midbf = qkvbf + rows * 3 * H_;          // [4096][4096]
  unsigned short* aoutbf= midbf + rows * MLPH_;           // [4096][1024]

  hipMemcpyAsync(hres, hs, rows * H_ * sizeof(float), hipMemcpyDeviceToDevice, stream);

  for (int l = 0; l < 2; l++) {
    wconv<<<dim3(96, 32), 256, 0, stream>>>(attn_w + (size_t)l * 1024 * 3072,
                                            wQ + (size_t)l * 3072 * 1024, 1024, 3072);
    wconv<<<dim3(32, 32), 256, 0, stream>>>(proj_w + (size_t)l * 1024 * 1024,
                                            wP + (size_t)l * 1024 * 1024, 1024, 1024);
    wconv<<<dim3(128, 32), 256, 0, stream>>>(fc_w + (size_t)l * 1024 * 4096,
                                             wF1 + (size_t)l * 4096 * 1024, 1024, 4096);
    wconv<<<dim3(32, 128), 256, 0, stream>>>(fc2_w + (size_t)l * 4096 * 1024,
                                             wF2 + (size_t)l * 1024 * 4096, 4096, 1024);
  }

  for (int l = 0; l < 2; l++) {
    ln_kernel<<<rows, 256, 0, stream>>>(hres, ln1_g + l * H_, ln1_b + l * H_, xbf);
    gemm_mfma<0><<<dim3(24, 32), 256, 0, stream>>>(
        xbf, wQ + (size_t)l * 3072 * 1024, attn_b + (size_t)l * 3072, nullptr,
        qkvbf, 4096, 3072, 1024);
    rope_bf<<<8192, 256, 0, stream>>>(qkvbf, pos);
    attn2<<<dim3(16, 16, 4), 256, 0, stream>>>(qkvbf, aoutbf);
    gemm_mfma<2><<<dim3(8, 32), 256, 0, stream>>>(
        aoutbf, wP + (size_t)l * 1024 * 1024, proj_b + (size_t)l * 1024, hres,
        hres, 4096, 1024, 1024);
    ln_kernel<<<rows, 256, 0, stream>>>(hres, ln2_g + l * H_, ln2_b + l * H_, xbf);
    gemm_mfma<1><<<dim3(32, 32), 256, 0, stream>>>(
        xbf, wF1 + (size_t)l * 4096 * 1024, fc_b + (size_t)l * 4096, nullptr,
        midbf, 4096, 4096, 1024);
    gemm_mfma<2><<<dim3(8, 32), 256, 0, stream>>>(
        midbf, wF2 + (size_t)l * 1024 * 4096, fc2_b + (size_t)l * 1024, hres,
        hres, 4096, 1024, 4096);
  }
}

// Round 3
// 683.029 us; speedup vs baseline: 13.8588x; 1.5110x over previous
//
#include <hip/hip_runtime.h>

#define B_ 4
#define S_ 1024
#define H_ 1024
#define NH_ 16
#define DK_ 64
#define MLPH_ 4096
#define EPS_ 1e-5f

typedef __attribute__((ext_vector_type(8))) short short8_t;
typedef __attribute__((ext_vector_type(8))) unsigned short ushort8_t;
typedef __attribute__((ext_vector_type(4))) float f32x4;

__device__ __forceinline__ unsigned short f2bf(float f) {
  unsigned int u = __float_as_uint(f);
  u = u + 0x7fffu + ((u >> 16) & 1u);  // RNE
  return (unsigned short)(u >> 16);
}
__device__ __forceinline__ float bf2f(unsigned short b) {
  return __uint_as_float(((unsigned int)b) << 16);
}

__device__ __forceinline__ void gload16(const void* g, void* l) {
  typedef const __attribute__((address_space(1))) unsigned int GU;
  typedef __attribute__((address_space(3))) unsigned int LU;
  __builtin_amdgcn_global_load_lds((GU*)(size_t)g, (LU*)(unsigned int)(size_t)l, 16, 0, 0);
}

__device__ __forceinline__ float gelu_tanh(float x) {
  float x3 = x * x * x;
  return 0.5f * x * (1.0f + tanhf(0.7978845608028654f * (x + 0.044715f * x3)));
}

// ---------------- weight fp32 [K,N] -> bf16 [N,K] transpose ----------------
__global__ __launch_bounds__(256) void wconv(const float* __restrict__ src,
                                             unsigned short* __restrict__ dst,
                                             int K, int N) {
  __shared__ float t[32][33];
  int n0 = blockIdx.x * 32, k0 = blockIdx.y * 32;
  int tid = threadIdx.x;
  int r = tid >> 3, c = (tid & 7) * 4;
  const float* s = src + (size_t)(k0 + r) * N + n0 + c;
  float4 v = *(const float4*)s;
  t[r][c] = v.x; t[r][c + 1] = v.y; t[r][c + 2] = v.z; t[r][c + 3] = v.w;
  __syncthreads();
  ushort4 o;
  o.x = f2bf(t[c + 0][r]); o.y = f2bf(t[c + 1][r]);
  o.z = f2bf(t[c + 2][r]); o.w = f2bf(t[c + 3][r]);
  *(ushort4*)(dst + (size_t)(n0 + r) * K + k0 + c) = o;
}

// ---------------- LayerNorm -> bf16 out ----------------
__global__ __launch_bounds__(256) void ln_kernel(const float* __restrict__ x,
                                                 const float* __restrict__ g,
                                                 const float* __restrict__ b,
                                                 unsigned short* __restrict__ y) {
  int row = blockIdx.x, tid = threadIdx.x;
  const float* xp = x + (size_t)row * H_;
  float4 v = *((const float4*)xp + tid);
  float s  = v.x + v.y + v.z + v.w;
  float s2 = v.x * v.x + v.y * v.y + v.z * v.z + v.w * v.w;
  #pragma unroll
  for (int o = 1; o < 64; o <<= 1) {
    s  += __shfl_xor(s, o, 64);
    s2 += __shfl_xor(s2, o, 64);
  }
  __shared__ float r1[4], r2[4];
  if ((tid & 63) == 0) { r1[tid >> 6] = s; r2[tid >> 6] = s2; }
  __syncthreads();
  s  = r1[0] + r1[1] + r1[2] + r1[3];
  s2 = r2[0] + r2[1] + r2[2] + r2[3];
  float mean = s * (1.0f / H_);
  float var  = s2 * (1.0f / H_) - mean * mean;
  float inv  = rsqrtf(var + EPS_);
  float4 gv = *((const float4*)g + tid);
  float4 bv = *((const float4*)b + tid);
  ushort4 o;
  o.x = f2bf((v.x - mean) * inv * gv.x + bv.x);
  o.y = f2bf((v.y - mean) * inv * gv.y + bv.y);
  o.z = f2bf((v.z - mean) * inv * gv.z + bv.z);
  o.w = f2bf((v.w - mean) * inv * gv.w + bv.w);
  *(ushort4*)(y + (size_t)row * H_ + tid * 4) = o;
}

// ---------------- RoPE in-place on qkv bf16 [B,S,3H] ----------------
__global__ __launch_bounds__(256) void rope_bf(unsigned short* qkv, const int* __restrict__ pos) {
  int idx = blockIdx.x * 256 + threadIdx.x;  // over B*S*NH*32
  int d = idx & 31;
  int hh = (idx >> 5) & 15;
  int s = (idx >> 9) & 1023;
  int b = idx >> 19;
  size_t base = ((size_t)(b * S_ + s)) * 3072 + hh * 64;
  float inv = __expf(-9.210340371976184f * ((float)d * 0.03125f));  // 10000^(-d/32)
  float th = (float)pos[s] * inv;
  float cs = cosf(th), sn = sinf(th);
  unsigned short* qp = qkv + base;
  unsigned short* kp = qkv + base + 1024;
  float q0 = bf2f(qp[d]), q1 = bf2f(qp[d + 32]);
  float k0 = bf2f(kp[d]), k1 = bf2f(kp[d + 32]);
  qp[d]      = f2bf(q0 * cs - q1 * sn);
  qp[d + 32] = f2bf(q1 * cs + q0 * sn);
  kp[d]      = f2bf(k0 * cs - k1 * sn);
  kp[d + 32] = f2bf(k1 * cs + k0 * sn);
}

// ---------------- bf16 MFMA GEMM: 128x128 tile, BK=32, 4 waves ----------------
template <int MODE>
__global__ __launch_bounds__(256) void gemm_mfma(
    const unsigned short* __restrict__ A, const unsigned short* __restrict__ Bt,
    const float* __restrict__ bias, const float* __restrict__ resid,
    void* __restrict__ outp, int M, int N, int K) {
  __shared__ __align__(16) unsigned short As[128 * 32];
  __shared__ __align__(16) unsigned short Bs[128 * 32];
  int tid = threadIdx.x;
  int w = tid >> 6, lane = tid & 63;
  int m0 = blockIdx.y * 128, n0 = blockIdx.x * 128;
  int wr = w >> 1, wc = w & 1;
  f32x4 acc[4][4];
  #pragma unroll
  for (int m = 0; m < 4; m++)
    #pragma unroll
    for (int n = 0; n < 4; n++) {
      acc[m][n][0] = 0.f; acc[m][n][1] = 0.f; acc[m][n][2] = 0.f; acc[m][n][3] = 0.f;
    }
  int arow = lane >> 2, acol = (lane & 3) * 8;
  int c0 = w * 2, c1 = w * 2 + 1;
  const unsigned short* A0 = A + (size_t)(m0 + c0 * 16 + arow) * K + acol;
  const unsigned short* A1 = A + (size_t)(m0 + c1 * 16 + arow) * K + acol;
  const unsigned short* B0 = Bt + (size_t)(n0 + c0 * 16 + arow) * K + acol;
  const unsigned short* B1 = Bt + (size_t)(n0 + c1 * 16 + arow) * K + acol;
  int fr = lane & 15, krow = (lane >> 4) * 8;
  for (int k0 = 0; k0 < K; k0 += 32) {
    __syncthreads();
    gload16(A0 + k0, (char*)As + c0 * 1024);
    gload16(A1 + k0, (char*)As + c1 * 1024);
    gload16(B0 + k0, (char*)Bs + c0 * 1024);
    gload16(B1 + k0, (char*)Bs + c1 * 1024);
    __syncthreads();
    short8_t af[4], bfr[4];
    #pragma unroll
    for (int m = 0; m < 4; m++)
      af[m] = *(const short8_t*)&As[(wr * 64 + m * 16 + fr) * 32 + krow];
    #pragma unroll
    for (int n = 0; n < 4; n++)
      bfr[n] = *(const short8_t*)&Bs[(wc * 64 + n * 16 + fr) * 32 + krow];
    #pragma unroll
    for (int m = 0; m < 4; m++)
      #pragma unroll
      for (int n = 0; n < 4; n++)
        acc[m][n] = __builtin_amdgcn_mfma_f32_16x16x32_bf16(af[m], bfr[n], acc[m][n], 0, 0, 0);
  }
  int orow = (lane >> 4) * 4;
  #pragma unroll
  for (int n = 0; n < 4; n++) {
    int col = n0 + wc * 64 + n * 16 + fr;
    float bv = bias[col];
    #pragma unroll
    for (int m = 0; m < 4; m++) {
      int row = m0 + wr * 64 + m * 16 + orow;
      #pragma unroll
      for (int r = 0; r < 4; r++) {
        float v = acc[m][n][r] + bv;
        size_t idx = (size_t)(row + r) * N + col;
        if (MODE == 2)      ((float*)outp)[idx] = resid[idx] + v;
        else if (MODE == 1) ((unsigned short*)outp)[idx] = f2bf(gelu_tanh(v));
        else                ((unsigned short*)outp)[idx] = f2bf(v);
      }
    }
  }
}

// ---------------- MFMA flash attention: 4 waves x 16 q-rows, KVBLK=64 ----------------
__global__ __launch_bounds__(256) void attn3(const unsigned short* __restrict__ qkv,
                                             unsigned short* __restrict__ aout) {
  __shared__ __align__(16) unsigned short Ks[64 * 64];   // [kv][d], swizzled
  __shared__ __align__(16) unsigned short Vt[64 * 64];   // [d][kv], swizzled
  __shared__ __align__(16) unsigned short Ps[4][16 * 64]; // per-wave P [row][kv], swizzled
  int tid = threadIdx.x;
  int w = tid >> 6, lane = tid & 63;
  int fr = lane & 15, kg = lane >> 4;
  int qt = (int)gridDim.x - 1 - (int)blockIdx.x;  // heavy tiles first
  int q0 = qt * 64;
  int head = blockIdx.y, b = blockIdx.z;
  const unsigned short* base = qkv + ((size_t)b * S_) * 3072 + head * 64;

  // Q A-fragments: rows q0 + w*16 + fr, k-slices [kg*8, kg*8+8) and +32
  const unsigned short* qp = base + (size_t)(q0 + w * 16 + fr) * 3072 + kg * 8;
  short8_t qa0 = *(const short8_t*)qp;
  short8_t qa1 = *(const short8_t*)(qp + 32);

  f32x4 acc[4];    // O accumulator: [n dk-tile][r]
  float mrun[4], lrun[4];
  #pragma unroll
  for (int n = 0; n < 4; n++) { acc[n][0] = 0.f; acc[n][1] = 0.f; acc[n][2] = 0.f; acc[n][3] = 0.f; }
  #pragma unroll
  for (int r = 0; r < 4; r++) { mrun[r] = -3.0e38f; lrun[r] = 0.f; }

  int skv = lane;       // staging: kv row
  int sd0 = w * 16;     // staging: dk offset

  for (int t = 0; t <= qt; t++) {
    __syncthreads();
    {
      const unsigned short* kp = base + 1024 + (size_t)(t * 64 + skv) * 3072 + sd0;
      const unsigned short* vp = base + 2048 + (size_t)(t * 64 + skv) * 3072 + sd0;
      short8_t ka = *(const short8_t*)kp;
      short8_t kb = *(const short8_t*)(kp + 8);
      short8_t va = *(const short8_t*)vp;
      short8_t vb = *(const short8_t*)(vp + 8);
      unsigned kbyte = skv * 128 + sd0 * 2;
      unsigned ksw = (skv & 7) << 4;
      *(short8_t*)((char*)Ks + (kbyte ^ ksw)) = ka;
      *(short8_t*)((char*)Ks + ((kbyte + 16) ^ ksw)) = kb;
      #pragma unroll
      for (int j = 0; j < 8; j++) {
        int d0 = sd0 + j, d1 = sd0 + 8 + j;
        *(unsigned short*)((char*)Vt + ((d0 * 128 + skv * 2) ^ ((d0 & 7) << 4))) = (unsigned short)va[j];
        *(unsigned short*)((char*)Vt + ((d1 * 128 + skv * 2) ^ ((d1 & 7) << 4))) = (unsigned short)vb[j];
      }
    }
    __syncthreads();
    // ---- QK^T: S[16 x 64] per wave ----
    f32x4 s[4];
    #pragma unroll
    for (int n = 0; n < 4; n++) {
      int kvrow = n * 16 + fr;
      unsigned sw = (kvrow & 7) << 4;
      short8_t b0 = *(const short8_t*)((char*)Ks + ((kvrow * 128 + kg * 16) ^ sw));
      short8_t b1 = *(const short8_t*)((char*)Ks + ((kvrow * 128 + 64 + kg * 16) ^ sw));
      f32x4 z; z[0] = 0.f; z[1] = 0.f; z[2] = 0.f; z[3] = 0.f;
      z = __builtin_amdgcn_mfma_f32_16x16x32_bf16(qa0, b0, z, 0, 0, 0);
      z = __builtin_amdgcn_mfma_f32_16x16x32_bf16(qa1, b1, z, 0, 0, 0);
      s[n] = z;
    }
    // ---- online softmax ----
    bool diag = (t == qt);
    float p[4][4];
    #pragma unroll
    for (int r = 0; r < 4; r++) {
      int qrow = w * 16 + kg * 4 + r;  // within-block q row
      float rm = -3.0e38f;
      #pragma unroll
      for (int n = 0; n < 4; n++) {
        float sv = s[n][r] * 0.125f;
        if (diag && (n * 16 + fr > qrow)) sv = -3.0e38f;
        s[n][r] = sv;
        rm = fmaxf(rm, sv);
      }
      rm = fmaxf(rm, __shfl_xor(rm, 1, 64));
      rm = fmaxf(rm, __shfl_xor(rm, 2, 64));
      rm = fmaxf(rm, __shfl_xor(rm, 4, 64));
      rm = fmaxf(rm, __shfl_xor(rm, 8, 64));
      float mn = fmaxf(mrun[r], rm);
      float sc = __expf(mrun[r] - mn);
      mrun[r] = mn;
      float ls = 0.f;
      #pragma unroll
      for (int n = 0; n < 4; n++) {
        float e = __expf(s[n][r] - mn);
        p[n][r] = e;
        ls += e;
      }
      ls += __shfl_xor(ls, 1, 64);
      ls += __shfl_xor(ls, 2, 64);
      ls += __shfl_xor(ls, 4, 64);
      ls += __shfl_xor(ls, 8, 64);
      lrun[r] = lrun[r] * sc + ls;
      #pragma unroll
      for (int n = 0; n < 4; n++) acc[n][r] *= sc;
    }
    // ---- P -> per-wave LDS (bf16, A-frag layout, swizzled) ----
    #pragma unroll
    for (int n = 0; n < 4; n++)
      #pragma unroll
      for (int r = 0; r < 4; r++) {
        int row = kg * 4 + r, col = n * 16 + fr;
        *(unsigned short*)((char*)Ps[w] + ((row * 128 + col * 2) ^ ((row & 7) << 4))) = f2bf(p[n][r]);
      }
    asm volatile("s_waitcnt lgkmcnt(0)" ::: "memory");
    // ---- PV ----
    unsigned psw = (fr & 7) << 4;
    short8_t pa0 = *(const short8_t*)((char*)Ps[w] + ((fr * 128 + kg * 16) ^ psw));
    short8_t pa1 = *(const short8_t*)((char*)Ps[w] + ((fr * 128 + 64 + kg * 16) ^ psw));
    #pragma unroll
    for (int n = 0; n < 4; n++) {
      int d = n * 16 + fr;
      unsigned sw = (d & 7) << 4;
      short8_t v0 = *(const short8_t*)((char*)Vt + ((d * 128 + kg * 16) ^ sw));
      short8_t v1 = *(const short8_t*)((char*)Vt + ((d * 128 + 64 + kg * 16) ^ sw));
      acc[n] = __builtin_amdgcn_mfma_f32_16x16x32_bf16(pa0, v0, acc[n], 0, 0, 0);
      acc[n] = __builtin_amdgcn_mfma_f32_16x16x32_bf16(pa1, v1, acc[n], 0, 0, 0);
    }
  }
  // ---- epilogue ----
  #pragma unroll
  for (int r = 0; r < 4; r++) {
    float inv = 1.0f / lrun[r];
    size_t row = (size_t)b * S_ + q0 + w * 16 + kg * 4 + r;
    unsigned short* op = aout + row * H_ + head * 64 + fr;
    #pragma unroll
    for (int n = 0; n < 4; n++) op[n * 16] = f2bf(acc[n][r] * inv);
  }
}

extern "C" void kernel_launch(void* const* d_in, const int* in_sizes, int n_in,
                              void* d_out, int out_size, void* d_ws, size_t ws_size,
                              hipStream_t stream) {
  const float* hs     = (const float*)d_in[0];
  const float* attn_w = (const float*)d_in[1];
  const float* attn_b = (const float*)d_in[2];
  const float* proj_w = (const float*)d_in[3];
  const float* proj_b = (const float*)d_in[4];
  const float* fc_w   = (const float*)d_in[5];
  const float* fc_b   = (const float*)d_in[6];
  const float* fc2_w  = (const float*)d_in[7];
  const float* fc2_b  = (const float*)d_in[8];
  const float* ln1_g  = (const float*)d_in[9];
  const float* ln1_b  = (const float*)d_in[10];
  const float* ln2_g  = (const float*)d_in[11];
  const float* ln2_b  = (const float*)d_in[12];
  const int*   pos    = (const int*)d_in[13];

  float* hres = (float*)d_out;
  const size_t rows = (size_t)B_ * S_;  // 4096

  unsigned short* wQ    = (unsigned short*)d_ws;          // [L][3072][1024]
  unsigned short* wP    = wQ  + (size_t)2 * 3072 * 1024;  // [L][1024][1024]
  unsigned short* wF1   = wP  + (size_t)2 * 1024 * 1024;  // [L][4096][1024]
  unsigned short* wF2   = wF1 + (size_t)2 * 4096 * 1024;  // [L][1024][4096]
  unsigned short* xbf   = wF2 + (size_t)2 * 1024 * 4096;  // [4096][1024]
  unsigned short* qkvbf = xbf + rows * H_;                // [4096][3072]
  unsigned short* midbf = qkvbf + rows * 3 * H_;          // [4096][4096]
  unsigned short* aoutbf= midbf + rows * MLPH_;           // [4096][1024]

  hipMemcpyAsync(hres, hs, rows * H_ * sizeof(float), hipMemcpyDeviceToDevice, stream);

  for (int l = 0; l < 2; l++) {
    wconv<<<dim3(96, 32), 256, 0, stream>>>(attn_w + (size_t)l * 1024 * 3072,
                                            wQ + (size_t)l * 3072 * 1024, 1024, 3072);
    wconv<<<dim3(32, 32), 256, 0, stream>>>(proj_w + (size_t)l * 1024 * 1024,
                                            wP + (size_t)l * 1024 * 1024, 1024, 1024);
    wconv<<<dim3(128, 32), 256, 0, stream>>>(fc_w + (size_t)l * 1024 * 4096,
                                             wF1 + (size_t)l * 4096 * 1024, 1024, 4096);
    wconv<<<dim3(32, 128), 256, 0, stream>>>(fc2_w + (size_t)l * 4096 * 1024,
                                             wF2 + (size_t)l * 1024 * 4096, 4096, 1024);
  }

  for (int l = 0; l < 2; l++) {
    ln_kernel<<<rows, 256, 0, stream>>>(hres, ln1_g + l * H_, ln1_b + l * H_, xbf);
    gemm_mfma<0><<<dim3(24, 32), 256, 0, stream>>>(
        xbf, wQ + (size_t)l * 3072 * 1024, attn_b + (size_t)l * 3072, nullptr,
        qkvbf, 4096, 3072, 1024);
    rope_bf<<<8192, 256, 0, stream>>>(qkvbf, pos);
    attn3<<<dim3(16, 16, 4), 256, 0, stream>>>(qkvbf, aoutbf);
    gemm_mfma<2><<<dim3(8, 32), 256, 0, stream>>>(
        aoutbf, wP + (size_t)l * 1024 * 1024, proj_b + (size_t)l * 1024, hres,
        hres, 4096, 1024, 1024);
    ln_kernel<<<rows, 256, 0, stream>>>(hres, ln2_g + l * H_, ln2_b + l * H_, xbf);
    gemm_mfma<1><<<dim3(32, 32), 256, 0, stream>>>(
        xbf, wF1 + (size_t)l * 4096 * 1024, fc_b + (size_t)l * 4096, nullptr,
        midbf, 4096, 4096, 1024);
    gemm_mfma<2><<<dim3(8, 32), 256, 0, stream>>>(
        midbf, wF2 + (size_t)l * 1024 * 4096, fc2_b + (size_t)l * 1024, hres,
        hres, 4096, 1024, 4096);
  }
}

// Round 4
// 612.890 us; speedup vs baseline: 15.4448x; 1.1144x over previous
//
#include <hip/hip_runtime.h>

#define B_ 4
#define S_ 1024
#define H_ 1024
#define NH_ 16
#define DK_ 64
#define MLPH_ 4096
#define EPS_ 1e-5f

typedef __attribute__((ext_vector_type(8))) short short8_t;
typedef __attribute__((ext_vector_type(8))) unsigned short ushort8_t;
typedef __attribute__((ext_vector_type(4))) float f32x4;

__device__ __forceinline__ unsigned short f2bf(float f) {
  unsigned int u = __float_as_uint(f);
  u = u + 0x7fffu + ((u >> 16) & 1u);  // RNE
  return (unsigned short)(u >> 16);
}
__device__ __forceinline__ float bf2f(unsigned short b) {
  return __uint_as_float(((unsigned int)b) << 16);
}

__device__ __forceinline__ void gload16(const void* g, void* l) {
  typedef const __attribute__((address_space(1))) unsigned int GU;
  typedef __attribute__((address_space(3))) unsigned int LU;
  __builtin_amdgcn_global_load_lds((GU*)(size_t)g, (LU*)(unsigned int)(size_t)l, 16, 0, 0);
}

__device__ __forceinline__ float gelu_tanh(float x) {
  float x3 = x * x * x;
  return 0.5f * x * (1.0f + tanhf(0.7978845608028654f * (x + 0.044715f * x3)));
}

// ---------------- weight fp32 [K,N] -> bf16 [N,K] transpose ----------------
__global__ __launch_bounds__(256) void wconv(const float* __restrict__ src,
                                             unsigned short* __restrict__ dst,
                                             int K, int N) {
  __shared__ float t[32][33];
  int n0 = blockIdx.x * 32, k0 = blockIdx.y * 32;
  int tid = threadIdx.x;
  int r = tid >> 3, c = (tid & 7) * 4;
  const float* s = src + (size_t)(k0 + r) * N + n0 + c;
  float4 v = *(const float4*)s;
  t[r][c] = v.x; t[r][c + 1] = v.y; t[r][c + 2] = v.z; t[r][c + 3] = v.w;
  __syncthreads();
  ushort4 o;
  o.x = f2bf(t[c + 0][r]); o.y = f2bf(t[c + 1][r]);
  o.z = f2bf(t[c + 2][r]); o.w = f2bf(t[c + 3][r]);
  *(ushort4*)(dst + (size_t)(n0 + r) * K + k0 + c) = o;
}

// ---------------- LayerNorm -> bf16 out ----------------
__global__ __launch_bounds__(256) void ln_kernel(const float* __restrict__ x,
                                                 const float* __restrict__ g,
                                                 const float* __restrict__ b,
                                                 unsigned short* __restrict__ y) {
  int row = blockIdx.x, tid = threadIdx.x;
  const float* xp = x + (size_t)row * H_;
  float4 v = *((const float4*)xp + tid);
  float s  = v.x + v.y + v.z + v.w;
  float s2 = v.x * v.x + v.y * v.y + v.z * v.z + v.w * v.w;
  #pragma unroll
  for (int o = 1; o < 64; o <<= 1) {
    s  += __shfl_xor(s, o, 64);
    s2 += __shfl_xor(s2, o, 64);
  }
  __shared__ float r1[4], r2[4];
  if ((tid & 63) == 0) { r1[tid >> 6] = s; r2[tid >> 6] = s2; }
  __syncthreads();
  s  = r1[0] + r1[1] + r1[2] + r1[3];
  s2 = r2[0] + r2[1] + r2[2] + r2[3];
  float mean = s * (1.0f / H_);
  float var  = s2 * (1.0f / H_) - mean * mean;
  float inv  = rsqrtf(var + EPS_);
  float4 gv = *((const float4*)g + tid);
  float4 bv = *((const float4*)b + tid);
  ushort4 o;
  o.x = f2bf((v.x - mean) * inv * gv.x + bv.x);
  o.y = f2bf((v.y - mean) * inv * gv.y + bv.y);
  o.z = f2bf((v.z - mean) * inv * gv.z + bv.z);
  o.w = f2bf((v.w - mean) * inv * gv.w + bv.w);
  *(ushort4*)(y + (size_t)row * H_ + tid * 4) = o;
}

// ---------------- RoPE in-place on qkv bf16 [B,S,3H] ----------------
__global__ __launch_bounds__(256) void rope_bf(unsigned short* qkv, const int* __restrict__ pos) {
  int idx = blockIdx.x * 256 + threadIdx.x;  // over B*S*NH*32
  int d = idx & 31;
  int hh = (idx >> 5) & 15;
  int s = (idx >> 9) & 1023;
  int b = idx >> 19;
  size_t base = ((size_t)(b * S_ + s)) * 3072 + hh * 64;
  float inv = __expf(-9.210340371976184f * ((float)d * 0.03125f));  // 10000^(-d/32)
  float th = (float)pos[s] * inv;
  float cs = cosf(th), sn = sinf(th);
  unsigned short* qp = qkv + base;
  unsigned short* kp = qkv + base + 1024;
  float q0 = bf2f(qp[d]), q1 = bf2f(qp[d + 32]);
  float k0 = bf2f(kp[d]), k1 = bf2f(kp[d + 32]);
  qp[d]      = f2bf(q0 * cs - q1 * sn);
  qp[d + 32] = f2bf(q1 * cs + q0 * sn);
  kp[d]      = f2bf(k0 * cs - k1 * sn);
  kp[d + 32] = f2bf(k1 * cs + k0 * sn);
}

// ---------------- bf16 MFMA GEMM: 128xBN tile, BK=64, 4 waves ----------------
// A:[M,K] bf16 row-major; Bt:[N,K] bf16 row-major (W^T).
// NT = 16-col tiles per wave (4 -> BN=128, 2 -> BN=64).
// LDS rows are 128B (64 bf16); slot-swizzled: physical 16B slot = logical ^ (row&7).
// Staged via pre-swizzled GLOBAL source (involution), read with matching XOR.
// MODE 0: bf16 = A*W+bias; MODE 1: bf16 = gelu(...); MODE 2: f32 = resid+...
template <int MODE, int NT>
__global__ __launch_bounds__(256) void gemm_mfma(
    const unsigned short* __restrict__ A, const unsigned short* __restrict__ Bt,
    const float* __restrict__ bias, const float* __restrict__ resid,
    void* __restrict__ outp, int M, int N, int K) {
  constexpr int BN = NT * 32;
  constexpr int CB = BN / 32;  // B chunks (8 rows) per wave
  __shared__ __align__(16) unsigned short As[128 * 64];
  __shared__ __align__(16) unsigned short Bs[BN * 64];
  int tid = threadIdx.x;
  int w = tid >> 6, lane = tid & 63;
  int m0 = blockIdx.y * 128, n0 = blockIdx.x * BN;
  int wr = w >> 1, wc = w & 1;
  int fr = lane & 15, kg = lane >> 4;
  f32x4 acc[4][NT];
  #pragma unroll
  for (int m = 0; m < 4; m++)
    #pragma unroll
    for (int n = 0; n < NT; n++) {
      acc[m][n][0] = 0.f; acc[m][n][1] = 0.f; acc[m][n][2] = 0.f; acc[m][n][3] = 0.f;
    }
  // staging: chunk = 8 rows x 128B; lane -> row srow=l>>3, swizzled 16B slot (l&7)^srow
  int srow = lane >> 3;
  int scol = ((lane & 7) ^ srow) * 8;  // element offset of this lane's 16B
  const unsigned short* Ap = A  + (size_t)(m0 + w * 32 + srow) * K + scol;
  const unsigned short* Bp = Bt + (size_t)(n0 + w * (8 * CB) + srow) * K + scol;
  char* AsB = (char*)As + w * 4096;
  char* BsB = (char*)Bs + w * CB * 1024;
  int sx = (fr & 7);  // read-side swizzle key
  for (int k0 = 0; k0 < K; k0 += 64) {
    __syncthreads();
    #pragma unroll
    for (int i = 0; i < 4; i++)
      gload16(Ap + k0 + (size_t)i * 8 * K, AsB + i * 1024);
    #pragma unroll
    for (int i = 0; i < CB; i++)
      gload16(Bp + k0 + (size_t)i * 8 * K, BsB + i * 1024);
    __syncthreads();
    #pragma unroll
    for (int kk = 0; kk < 2; kk++) {
      int slot = ((kk * 4 + kg) ^ sx) << 4;
      short8_t af[4], bfr[NT];
      #pragma unroll
      for (int m = 0; m < 4; m++)
        af[m] = *(const short8_t*)((char*)As + (wr * 64 + m * 16 + fr) * 128 + slot);
      #pragma unroll
      for (int n = 0; n < NT; n++)
        bfr[n] = *(const short8_t*)((char*)Bs + (wc * (NT * 16) + n * 16 + fr) * 128 + slot);
      #pragma unroll
      for (int m = 0; m < 4; m++)
        #pragma unroll
        for (int n = 0; n < NT; n++)
          acc[m][n] = __builtin_amdgcn_mfma_f32_16x16x32_bf16(af[m], bfr[n], acc[m][n], 0, 0, 0);
    }
  }
  #pragma unroll
  for (int n = 0; n < NT; n++) {
    int col = n0 + wc * (NT * 16) + n * 16 + fr;
    float bv = bias[col];
    #pragma unroll
    for (int m = 0; m < 4; m++) {
      int row = m0 + wr * 64 + m * 16 + kg * 4;
      #pragma unroll
      for (int r = 0; r < 4; r++) {
        float v = acc[m][n][r] + bv;
        size_t idx = (size_t)(row + r) * N + col;
        if (MODE == 2)      ((float*)outp)[idx] = resid[idx] + v;
        else if (MODE == 1) ((unsigned short*)outp)[idx] = f2bf(gelu_tanh(v));
        else                ((unsigned short*)outp)[idx] = f2bf(v);
      }
    }
  }
}

// ---------------- MFMA flash attention: 4 waves x 16 q-rows, KVBLK=64 ----------------
__global__ __launch_bounds__(256) void attn3(const unsigned short* __restrict__ qkv,
                                             unsigned short* __restrict__ aout) {
  __shared__ __align__(16) unsigned short Ks[64 * 64];   // [kv][d], swizzled
  __shared__ __align__(16) unsigned short Vt[64 * 64];   // [d][kv], swizzled
  __shared__ __align__(16) unsigned short Ps[4][16 * 64]; // per-wave P [row][kv], swizzled
  int tid = threadIdx.x;
  int w = tid >> 6, lane = tid & 63;
  int fr = lane & 15, kg = lane >> 4;
  int qt = (int)gridDim.x - 1 - (int)blockIdx.x;  // heavy tiles first
  int q0 = qt * 64;
  int head = blockIdx.y, b = blockIdx.z;
  const unsigned short* base = qkv + ((size_t)b * S_) * 3072 + head * 64;

  const unsigned short* qp = base + (size_t)(q0 + w * 16 + fr) * 3072 + kg * 8;
  short8_t qa0 = *(const short8_t*)qp;
  short8_t qa1 = *(const short8_t*)(qp + 32);

  f32x4 acc[4];    // O accumulator: [n dk-tile][r]
  float mrun[4], lrun[4];
  #pragma unroll
  for (int n = 0; n < 4; n++) { acc[n][0] = 0.f; acc[n][1] = 0.f; acc[n][2] = 0.f; acc[n][3] = 0.f; }
  #pragma unroll
  for (int r = 0; r < 4; r++) { mrun[r] = -3.0e38f; lrun[r] = 0.f; }

  int skv = lane;       // staging: kv row
  int sd0 = w * 16;     // staging: dk offset

  for (int t = 0; t <= qt; t++) {
    __syncthreads();
    {
      const unsigned short* kp = base + 1024 + (size_t)(t * 64 + skv) * 3072 + sd0;
      const unsigned short* vp = base + 2048 + (size_t)(t * 64 + skv) * 3072 + sd0;
      short8_t ka = *(const short8_t*)kp;
      short8_t kb = *(const short8_t*)(kp + 8);
      short8_t va = *(const short8_t*)vp;
      short8_t vb = *(const short8_t*)(vp + 8);
      unsigned kbyte = skv * 128 + sd0 * 2;
      unsigned ksw = (skv & 7) << 4;
      *(short8_t*)((char*)Ks + (kbyte ^ ksw)) = ka;
      *(short8_t*)((char*)Ks + ((kbyte + 16) ^ ksw)) = kb;
      #pragma unroll
      for (int j = 0; j < 8; j++) {
        int d0 = sd0 + j, d1 = sd0 + 8 + j;
        *(unsigned short*)((char*)Vt + ((d0 * 128 + skv * 2) ^ ((d0 & 7) << 4))) = (unsigned short)va[j];
        *(unsigned short*)((char*)Vt + ((d1 * 128 + skv * 2) ^ ((d1 & 7) << 4))) = (unsigned short)vb[j];
      }
    }
    __syncthreads();
    // ---- QK^T: S[16 x 64] per wave ----
    f32x4 s[4];
    #pragma unroll
    for (int n = 0; n < 4; n++) {
      int kvrow = n * 16 + fr;
      unsigned sw = (kvrow & 7) << 4;
      short8_t b0 = *(const short8_t*)((char*)Ks + ((kvrow * 128 + kg * 16) ^ sw));
      short8_t b1 = *(const short8_t*)((char*)Ks + ((kvrow * 128 + 64 + kg * 16) ^ sw));
      f32x4 z; z[0] = 0.f; z[1] = 0.f; z[2] = 0.f; z[3] = 0.f;
      z = __builtin_amdgcn_mfma_f32_16x16x32_bf16(qa0, b0, z, 0, 0, 0);
      z = __builtin_amdgcn_mfma_f32_16x16x32_bf16(qa1, b1, z, 0, 0, 0);
      s[n] = z;
    }
    // ---- online softmax ----
    bool diag = (t == qt);
    float p[4][4];
    #pragma unroll
    for (int r = 0; r < 4; r++) {
      int qrow = w * 16 + kg * 4 + r;
      float rm = -3.0e38f;
      #pragma unroll
      for (int n = 0; n < 4; n++) {
        float sv = s[n][r] * 0.125f;
        if (diag && (n * 16 + fr > qrow)) sv = -3.0e38f;
        s[n][r] = sv;
        rm = fmaxf(rm, sv);
      }
      rm = fmaxf(rm, __shfl_xor(rm, 1, 64));
      rm = fmaxf(rm, __shfl_xor(rm, 2, 64));
      rm = fmaxf(rm, __shfl_xor(rm, 4, 64));
      rm = fmaxf(rm, __shfl_xor(rm, 8, 64));
      float mn = fmaxf(mrun[r], rm);
      float sc = __expf(mrun[r] - mn);
      mrun[r] = mn;
      float ls = 0.f;
      #pragma unroll
      for (int n = 0; n < 4; n++) {
        float e = __expf(s[n][r] - mn);
        p[n][r] = e;
        ls += e;
      }
      ls += __shfl_xor(ls, 1, 64);
      ls += __shfl_xor(ls, 2, 64);
      ls += __shfl_xor(ls, 4, 64);
      ls += __shfl_xor(ls, 8, 64);
      lrun[r] = lrun[r] * sc + ls;
      #pragma unroll
      for (int n = 0; n < 4; n++) acc[n][r] *= sc;
    }
    // ---- P -> per-wave LDS (bf16, A-frag layout, swizzled) ----
    #pragma unroll
    for (int n = 0; n < 4; n++)
      #pragma unroll
      for (int r = 0; r < 4; r++) {
        int row = kg * 4 + r, col = n * 16 + fr;
        *(unsigned short*)((char*)Ps[w] + ((row * 128 + col * 2) ^ ((row & 7) << 4))) = f2bf(p[n][r]);
      }
    asm volatile("s_waitcnt lgkmcnt(0)" ::: "memory");
    // ---- PV ----
    unsigned psw = (fr & 7) << 4;
    short8_t pa0 = *(const short8_t*)((char*)Ps[w] + ((fr * 128 + kg * 16) ^ psw));
    short8_t pa1 = *(const short8_t*)((char*)Ps[w] + ((fr * 128 + 64 + kg * 16) ^ psw));
    #pragma unroll
    for (int n = 0; n < 4; n++) {
      int d = n * 16 + fr;
      unsigned sw = (d & 7) << 4;
      short8_t v0 = *(const short8_t*)((char*)Vt + ((d * 128 + kg * 16) ^ sw));
      short8_t v1 = *(const short8_t*)((char*)Vt + ((d * 128 + 64 + kg * 16) ^ sw));
      acc[n] = __builtin_amdgcn_mfma_f32_16x16x32_bf16(pa0, v0, acc[n], 0, 0, 0);
      acc[n] = __builtin_amdgcn_mfma_f32_16x16x32_bf16(pa1, v1, acc[n], 0, 0, 0);
    }
  }
  // ---- epilogue ----
  #pragma unroll
  for (int r = 0; r < 4; r++) {
    float inv = 1.0f / lrun[r];
    size_t row = (size_t)b * S_ + q0 + w * 16 + kg * 4 + r;
    unsigned short* op = aout + row * H_ + head * 64 + fr;
    #pragma unroll
    for (int n = 0; n < 4; n++) op[n * 16] = f2bf(acc[n][r] * inv);
  }
}

extern "C" void kernel_launch(void* const* d_in, const int* in_sizes, int n_in,
                              void* d_out, int out_size, void* d_ws, size_t ws_size,
                              hipStream_t stream) {
  const float* hs     = (const float*)d_in[0];
  const float* attn_w = (const float*)d_in[1];
  const float* attn_b = (const float*)d_in[2];
  const float* proj_w = (const float*)d_in[3];
  const float* proj_b = (const float*)d_in[4];
  const float* fc_w   = (const float*)d_in[5];
  const float* fc_b   = (const float*)d_in[6];
  const float* fc2_w  = (const float*)d_in[7];
  const float* fc2_b  = (const float*)d_in[8];
  const float* ln1_g  = (const float*)d_in[9];
  const float* ln1_b  = (const float*)d_in[10];
  const float* ln2_g  = (const float*)d_in[11];
  const float* ln2_b  = (const float*)d_in[12];
  const int*   pos    = (const int*)d_in[13];

  float* hres = (float*)d_out;
  const size_t rows = (size_t)B_ * S_;  // 4096

  unsigned short* wQ    = (unsigned short*)d_ws;          // [L][3072][1024]
  unsigned short* wP    = wQ  + (size_t)2 * 3072 * 1024;  // [L][1024][1024]
  unsigned short* wF1   = wP  + (size_t)2 * 1024 * 1024;  // [L][4096][1024]
  unsigned short* wF2   = wF1 + (size_t)2 * 4096 * 1024;  // [L][1024][4096]
  unsigned short* xbf   = wF2 + (size_t)2 * 1024 * 4096;  // [4096][1024]
  unsigned short* qkvbf = xbf + rows * H_;                // [4096][3072]
  unsigned short* midbf = qkvbf + rows * 3 * H_;          // [4096][4096]
  unsigned short* aoutbf= midbf + rows * MLPH_;           // [4096][1024]

  hipMemcpyAsync(hres, hs, rows * H_ * sizeof(float), hipMemcpyDeviceToDevice, stream);

  for (int l = 0; l < 2; l++) {
    wconv<<<dim3(96, 32), 256, 0, stream>>>(attn_w + (size_t)l * 1024 * 3072,
                                            wQ + (size_t)l * 3072 * 1024, 1024, 3072);
    wconv<<<dim3(32, 32), 256, 0, stream>>>(proj_w + (size_t)l * 1024 * 1024,
                                            wP + (size_t)l * 1024 * 1024, 1024, 1024);
    wconv<<<dim3(128, 32), 256, 0, stream>>>(fc_w + (size_t)l * 1024 * 4096,
                                             wF1 + (size_t)l * 4096 * 1024, 1024, 4096);
    wconv<<<dim3(32, 128), 256, 0, stream>>>(fc2_w + (size_t)l * 4096 * 1024,
                                             wF2 + (size_t)l * 1024 * 4096, 4096, 1024);
  }

  for (int l = 0; l < 2; l++) {
    ln_kernel<<<rows, 256, 0, stream>>>(hres, ln1_g + l * H_, ln1_b + l * H_, xbf);
    gemm_mfma<0, 4><<<dim3(24, 32), 256, 0, stream>>>(
        xbf, wQ + (size_t)l * 3072 * 1024, attn_b + (size_t)l * 3072, nullptr,
        qkvbf, 4096, 3072, 1024);
    rope_bf<<<8192, 256, 0, stream>>>(qkvbf, pos);
    attn3<<<dim3(16, 16, 4), 256, 0, stream>>>(qkvbf, aoutbf);
    gemm_mfma<2, 2><<<dim3(16, 32), 256, 0, stream>>>(
        aoutbf, wP + (size_t)l * 1024 * 1024, proj_b + (size_t)l * 1024, hres,
        hres, 4096, 1024, 1024);
    ln_kernel<<<rows, 256, 0, stream>>>(hres, ln2_g + l * H_, ln2_b + l * H_, xbf);
    gemm_mfma<1, 4><<<dim3(32, 32), 256, 0, stream>>>(
        xbf, wF1 + (size_t)l * 4096 * 1024, fc_b + (size_t)l * 4096, nullptr,
        midbf, 4096, 4096, 1024);
    gemm_mfma<2, 2><<<dim3(16, 32), 256, 0, stream>>>(
        midbf, wF2 + (size_t)l * 1024 * 4096, fc2_b + (size_t)l * 1024, hres,
        hres, 4096, 1024, 4096);
  }
}

// Round 5
// 565.246 us; speedup vs baseline: 16.7466x; 1.0843x over previous
//
#include <hip/hip_runtime.h>

#define B_ 4
#define S_ 1024
#define H_ 1024
#define NH_ 16
#define DK_ 64
#define MLPH_ 4096
#define EPS_ 1e-5f

typedef __attribute__((ext_vector_type(8))) short short8_t;
typedef __attribute__((ext_vector_type(8))) unsigned short ushort8_t;
typedef __attribute__((ext_vector_type(4))) float f32x4;

__device__ __forceinline__ unsigned short f2bf(float f) {
  unsigned int u = __float_as_uint(f);
  u = u + 0x7fffu + ((u >> 16) & 1u);  // RNE
  return (unsigned short)(u >> 16);
}
__device__ __forceinline__ float bf2f(unsigned short b) {
  return __uint_as_float(((unsigned int)b) << 16);
}

__device__ __forceinline__ void gload16(const void* g, void* l) {
  typedef const __attribute__((address_space(1))) unsigned int GU;
  typedef __attribute__((address_space(3))) unsigned int LU;
  __builtin_amdgcn_global_load_lds((GU*)(size_t)g, (LU*)(unsigned int)(size_t)l, 16, 0, 0);
}

__device__ __forceinline__ float gelu_tanh(float x) {
  float x3 = x * x * x;
  return 0.5f * x * (1.0f + tanhf(0.7978845608028654f * (x + 0.044715f * x3)));
}

// ---------------- weight fp32 [K,N] -> bf16 [N,K] transpose ----------------
__global__ __launch_bounds__(256) void wconv(const float* __restrict__ src,
                                             unsigned short* __restrict__ dst,
                                             int K, int N) {
  __shared__ float t[32][33];
  int n0 = blockIdx.x * 32, k0 = blockIdx.y * 32;
  int tid = threadIdx.x;
  int r = tid >> 3, c = (tid & 7) * 4;
  const float* s = src + (size_t)(k0 + r) * N + n0 + c;
  float4 v = *(const float4*)s;
  t[r][c] = v.x; t[r][c + 1] = v.y; t[r][c + 2] = v.z; t[r][c + 3] = v.w;
  __syncthreads();
  ushort4 o;
  o.x = f2bf(t[c + 0][r]); o.y = f2bf(t[c + 1][r]);
  o.z = f2bf(t[c + 2][r]); o.w = f2bf(t[c + 3][r]);
  *(ushort4*)(dst + (size_t)(n0 + r) * K + k0 + c) = o;
}

// ---------------- LayerNorm -> bf16 out ----------------
__global__ __launch_bounds__(256) void ln_kernel(const float* __restrict__ x,
                                                 const float* __restrict__ g,
                                                 const float* __restrict__ b,
                                                 unsigned short* __restrict__ y) {
  int row = blockIdx.x, tid = threadIdx.x;
  const float* xp = x + (size_t)row * H_;
  float4 v = *((const float4*)xp + tid);
  float s  = v.x + v.y + v.z + v.w;
  float s2 = v.x * v.x + v.y * v.y + v.z * v.z + v.w * v.w;
  #pragma unroll
  for (int o = 1; o < 64; o <<= 1) {
    s  += __shfl_xor(s, o, 64);
    s2 += __shfl_xor(s2, o, 64);
  }
  __shared__ float r1[4], r2[4];
  if ((tid & 63) == 0) { r1[tid >> 6] = s; r2[tid >> 6] = s2; }
  __syncthreads();
  s  = r1[0] + r1[1] + r1[2] + r1[3];
  s2 = r2[0] + r2[1] + r2[2] + r2[3];
  float mean = s * (1.0f / H_);
  float var  = s2 * (1.0f / H_) - mean * mean;
  float inv  = rsqrtf(var + EPS_);
  float4 gv = *((const float4*)g + tid);
  float4 bv = *((const float4*)b + tid);
  ushort4 o;
  o.x = f2bf((v.x - mean) * inv * gv.x + bv.x);
  o.y = f2bf((v.y - mean) * inv * gv.y + bv.y);
  o.z = f2bf((v.z - mean) * inv * gv.z + bv.z);
  o.w = f2bf((v.w - mean) * inv * gv.w + bv.w);
  *(ushort4*)(y + (size_t)row * H_ + tid * 4) = o;
}

// ---------------- RoPE in-place on qkv bf16 [B,S,3H] ----------------
__global__ __launch_bounds__(256) void rope_bf(unsigned short* qkv, const int* __restrict__ pos) {
  int idx = blockIdx.x * 256 + threadIdx.x;  // over B*S*NH*32
  int d = idx & 31;
  int hh = (idx >> 5) & 15;
  int s = (idx >> 9) & 1023;
  int b = idx >> 19;
  size_t base = ((size_t)(b * S_ + s)) * 3072 + hh * 64;
  float inv = __expf(-9.210340371976184f * ((float)d * 0.03125f));  // 10000^(-d/32)
  float th = (float)pos[s] * inv;
  float cs = cosf(th), sn = sinf(th);
  unsigned short* qp = qkv + base;
  unsigned short* kp = qkv + base + 1024;
  float q0 = bf2f(qp[d]), q1 = bf2f(qp[d + 32]);
  float k0 = bf2f(kp[d]), k1 = bf2f(kp[d + 32]);
  qp[d]      = f2bf(q0 * cs - q1 * sn);
  qp[d + 32] = f2bf(q1 * cs + q0 * sn);
  kp[d]      = f2bf(k0 * cs - k1 * sn);
  kp[d + 32] = f2bf(k1 * cs + k0 * sn);
}

// ---------------- bf16 MFMA GEMM: 128xBN tile, BK=64, 4 waves ----------------
template <int MODE, int NT>
__global__ __launch_bounds__(256) void gemm_mfma(
    const unsigned short* __restrict__ A, const unsigned short* __restrict__ Bt,
    const float* __restrict__ bias, const float* __restrict__ resid,
    void* __restrict__ outp, int M, int N, int K) {
  constexpr int BN = NT * 32;
  constexpr int CB = BN / 32;  // B chunks (8 rows) per wave
  __shared__ __align__(16) unsigned short As[128 * 64];
  __shared__ __align__(16) unsigned short Bs[BN * 64];
  int tid = threadIdx.x;
  int w = tid >> 6, lane = tid & 63;
  int m0 = blockIdx.y * 128, n0 = blockIdx.x * BN;
  int wr = w >> 1, wc = w & 1;
  int fr = lane & 15, kg = lane >> 4;
  f32x4 acc[4][NT];
  #pragma unroll
  for (int m = 0; m < 4; m++)
    #pragma unroll
    for (int n = 0; n < NT; n++) {
      acc[m][n][0] = 0.f; acc[m][n][1] = 0.f; acc[m][n][2] = 0.f; acc[m][n][3] = 0.f;
    }
  int srow = lane >> 3;
  int scol = ((lane & 7) ^ srow) * 8;  // pre-swizzled global source
  const unsigned short* Ap = A  + (size_t)(m0 + w * 32 + srow) * K + scol;
  const unsigned short* Bp = Bt + (size_t)(n0 + w * (8 * CB) + srow) * K + scol;
  char* AsB = (char*)As + w * 4096;
  char* BsB = (char*)Bs + w * CB * 1024;
  int sx = (fr & 7);  // read-side swizzle key
  for (int k0 = 0; k0 < K; k0 += 64) {
    __syncthreads();
    #pragma unroll
    for (int i = 0; i < 4; i++)
      gload16(Ap + k0 + (size_t)i * 8 * K, AsB + i * 1024);
    #pragma unroll
    for (int i = 0; i < CB; i++)
      gload16(Bp + k0 + (size_t)i * 8 * K, BsB + i * 1024);
    __syncthreads();
    #pragma unroll
    for (int kk = 0; kk < 2; kk++) {
      int slot = ((kk * 4 + kg) ^ sx) << 4;
      short8_t af[4], bfr[NT];
      #pragma unroll
      for (int m = 0; m < 4; m++)
        af[m] = *(const short8_t*)((char*)As + (wr * 64 + m * 16 + fr) * 128 + slot);
      #pragma unroll
      for (int n = 0; n < NT; n++)
        bfr[n] = *(const short8_t*)((char*)Bs + (wc * (NT * 16) + n * 16 + fr) * 128 + slot);
      #pragma unroll
      for (int m = 0; m < 4; m++)
        #pragma unroll
        for (int n = 0; n < NT; n++)
          acc[m][n] = __builtin_amdgcn_mfma_f32_16x16x32_bf16(af[m], bfr[n], acc[m][n], 0, 0, 0);
    }
  }
  #pragma unroll
  for (int n = 0; n < NT; n++) {
    int col = n0 + wc * (NT * 16) + n * 16 + fr;
    float bv = bias[col];
    #pragma unroll
    for (int m = 0; m < 4; m++) {
      int row = m0 + wr * 64 + m * 16 + kg * 4;
      #pragma unroll
      for (int r = 0; r < 4; r++) {
        float v = acc[m][n][r] + bv;
        size_t idx = (size_t)(row + r) * N + col;
        if (MODE == 2)      ((float*)outp)[idx] = resid[idx] + v;
        else if (MODE == 1) ((unsigned short*)outp)[idx] = f2bf(gelu_tanh(v));
        else                ((unsigned short*)outp)[idx] = f2bf(v);
      }
    }
  }
}

// ---------------- MFMA flash attention: 4 waves x 16 q-rows, KVBLK=64 ----------------
// Round 4: double-buffered reg-staged K/V (async-STAGE), defer-max softmax,
// lane-local l partial reduced once at end. One barrier per kv-tile.
__global__ __launch_bounds__(256) void attn3(const unsigned short* __restrict__ qkv,
                                             unsigned short* __restrict__ aout) {
  __shared__ __align__(16) unsigned short Ks[2][64 * 64];   // [kv][d], swizzled
  __shared__ __align__(16) unsigned short Vt[2][64 * 64];   // [d][kv], swizzled
  __shared__ __align__(16) unsigned short Ps[4][16 * 64];   // per-wave P, swizzled
  int tid = threadIdx.x;
  int w = tid >> 6, lane = tid & 63;
  int fr = lane & 15, kg = lane >> 4;
  int qt = (int)gridDim.x - 1 - (int)blockIdx.x;  // heavy tiles first
  int q0 = qt * 64;
  int head = blockIdx.y, b = blockIdx.z;
  const unsigned short* base = qkv + ((size_t)b * S_) * 3072 + head * 64;

  const unsigned short* qp = base + (size_t)(q0 + w * 16 + fr) * 3072 + kg * 8;
  short8_t qa0 = *(const short8_t*)qp;
  short8_t qa1 = *(const short8_t*)(qp + 32);

  f32x4 acc[4];    // O accumulator: [n dk-tile][r]
  float mrun[4], lrun[4];
  #pragma unroll
  for (int n = 0; n < 4; n++) { acc[n][0] = 0.f; acc[n][1] = 0.f; acc[n][2] = 0.f; acc[n][3] = 0.f; }
  #pragma unroll
  for (int r = 0; r < 4; r++) { mrun[r] = -3.0e38f; lrun[r] = 0.f; }

  int skv = lane;       // staging: kv row
  int sd0 = w * 16;     // staging: dk offset

  // prologue: load tile 0 into regs
  const unsigned short* kp0 = base + 1024 + (size_t)skv * 3072 + sd0;
  short8_t ka = *(const short8_t*)kp0;
  short8_t kb = *(const short8_t*)(kp0 + 8);
  short8_t va = *(const short8_t*)(kp0 + 1024);
  short8_t vb = *(const short8_t*)(kp0 + 1032);

  for (int t = 0; t <= qt; t++) {
    int cur = t & 1;
    // ---- write staged regs -> LDS[cur] ----
    {
      unsigned kbyte = skv * 128 + sd0 * 2;
      unsigned ksw = (skv & 7) << 4;
      *(short8_t*)((char*)Ks[cur] + (kbyte ^ ksw)) = ka;
      *(short8_t*)((char*)Ks[cur] + ((kbyte + 16) ^ ksw)) = kb;
      #pragma unroll
      for (int j = 0; j < 8; j++) {
        int d0 = sd0 + j, d1 = sd0 + 8 + j;
        *(unsigned short*)((char*)Vt[cur] + ((d0 * 128 + skv * 2) ^ ((d0 & 7) << 4))) = (unsigned short)va[j];
        *(unsigned short*)((char*)Vt[cur] + ((d1 * 128 + skv * 2) ^ ((d1 & 7) << 4))) = (unsigned short)vb[j];
      }
    }
    // ---- issue next tile's global loads (latency hides under compute) ----
    if (t < qt) {
      const unsigned short* kp = base + 1024 + (size_t)((t + 1) * 64 + skv) * 3072 + sd0;
      ka = *(const short8_t*)kp;
      kb = *(const short8_t*)(kp + 8);
      va = *(const short8_t*)(kp + 1024);
      vb = *(const short8_t*)(kp + 1032);
    }
    __syncthreads();
    // ---- QK^T: S[16 x 64] per wave ----
    f32x4 s[4];
    #pragma unroll
    for (int n = 0; n < 4; n++) {
      int kvrow = n * 16 + fr;
      unsigned sw = (kvrow & 7) << 4;
      short8_t b0 = *(const short8_t*)((char*)Ks[cur] + ((kvrow * 128 + kg * 16) ^ sw));
      short8_t b1 = *(const short8_t*)((char*)Ks[cur] + ((kvrow * 128 + 64 + kg * 16) ^ sw));
      f32x4 z; z[0] = 0.f; z[1] = 0.f; z[2] = 0.f; z[3] = 0.f;
      z = __builtin_amdgcn_mfma_f32_16x16x32_bf16(qa0, b0, z, 0, 0, 0);
      z = __builtin_amdgcn_mfma_f32_16x16x32_bf16(qa1, b1, z, 0, 0, 0);
      s[n] = z;
    }
    // ---- softmax: defer-max + lane-local l partial ----
    bool diag = (t == qt);
    float p[4][4], pmax[4];
    #pragma unroll
    for (int r = 0; r < 4; r++) {
      int qrow = w * 16 + kg * 4 + r;
      float rm = -3.0e38f;
      #pragma unroll
      for (int n = 0; n < 4; n++) {
        float sv = s[n][r] * 0.125f;
        if (diag && (n * 16 + fr > qrow)) sv = -3.0e38f;
        s[n][r] = sv;
        rm = fmaxf(rm, sv);
      }
      pmax[r] = rm;
    }
    bool need = (pmax[0] > mrun[0] + 8.f) | (pmax[1] > mrun[1] + 8.f) |
                (pmax[2] > mrun[2] + 8.f) | (pmax[3] > mrun[3] + 8.f);
    if (__any(need)) {
      #pragma unroll
      for (int r = 0; r < 4; r++) {
        float rm = pmax[r];
        rm = fmaxf(rm, __shfl_xor(rm, 1, 64));
        rm = fmaxf(rm, __shfl_xor(rm, 2, 64));
        rm = fmaxf(rm, __shfl_xor(rm, 4, 64));
        rm = fmaxf(rm, __shfl_xor(rm, 8, 64));
        float mn = fmaxf(mrun[r], rm);
        float sc = __expf(mrun[r] - mn);
        mrun[r] = mn;
        lrun[r] *= sc;
        #pragma unroll
        for (int n = 0; n < 4; n++) acc[n][r] *= sc;
      }
    }
    #pragma unroll
    for (int r = 0; r < 4; r++) {
      float ls = 0.f;
      #pragma unroll
      for (int n = 0; n < 4; n++) {
        float e = __expf(s[n][r] - mrun[r]);
        p[n][r] = e;
        ls += e;
      }
      lrun[r] += ls;  // per-lane partial; reduced once at end
    }
    // ---- P -> per-wave LDS (bf16, A-frag layout, swizzled) ----
    #pragma unroll
    for (int n = 0; n < 4; n++)
      #pragma unroll
      for (int r = 0; r < 4; r++) {
        int row = kg * 4 + r, col = n * 16 + fr;
        *(unsigned short*)((char*)Ps[w] + ((row * 128 + col * 2) ^ ((row & 7) << 4))) = f2bf(p[n][r]);
      }
    asm volatile("s_waitcnt lgkmcnt(0)" ::: "memory");
    // ---- PV ----
    unsigned psw = (fr & 7) << 4;
    short8_t pa0 = *(const short8_t*)((char*)Ps[w] + ((fr * 128 + kg * 16) ^ psw));
    short8_t pa1 = *(const short8_t*)((char*)Ps[w] + ((fr * 128 + 64 + kg * 16) ^ psw));
    #pragma unroll
    for (int n = 0; n < 4; n++) {
      int d = n * 16 + fr;
      unsigned sw = (d & 7) << 4;
      short8_t v0 = *(const short8_t*)((char*)Vt[cur] + ((d * 128 + kg * 16) ^ sw));
      short8_t v1 = *(const short8_t*)((char*)Vt[cur] + ((d * 128 + 64 + kg * 16) ^ sw));
      acc[n] = __builtin_amdgcn_mfma_f32_16x16x32_bf16(pa0, v0, acc[n], 0, 0, 0);
      acc[n] = __builtin_amdgcn_mfma_f32_16x16x32_bf16(pa1, v1, acc[n], 0, 0, 0);
    }
  }
  // ---- epilogue: reduce l across the 16-lane row group, normalize, store ----
  #pragma unroll
  for (int r = 0; r < 4; r++) {
    float ls = lrun[r];
    ls += __shfl_xor(ls, 1, 64);
    ls += __shfl_xor(ls, 2, 64);
    ls += __shfl_xor(ls, 4, 64);
    ls += __shfl_xor(ls, 8, 64);
    float inv = 1.0f / ls;
    size_t row = (size_t)b * S_ + q0 + w * 16 + kg * 4 + r;
    unsigned short* op = aout + row * H_ + head * 64 + fr;
    #pragma unroll
    for (int n = 0; n < 4; n++) op[n * 16] = f2bf(acc[n][r] * inv);
  }
}

extern "C" void kernel_launch(void* const* d_in, const int* in_sizes, int n_in,
                              void* d_out, int out_size, void* d_ws, size_t ws_size,
                              hipStream_t stream) {
  const float* hs     = (const float*)d_in[0];
  const float* attn_w = (const float*)d_in[1];
  const float* attn_b = (const float*)d_in[2];
  const float* proj_w = (const float*)d_in[3];
  const float* proj_b = (const float*)d_in[4];
  const float* fc_w   = (const float*)d_in[5];
  const float* fc_b   = (const float*)d_in[6];
  const float* fc2_w  = (const float*)d_in[7];
  const float* fc2_b  = (const float*)d_in[8];
  const float* ln1_g  = (const float*)d_in[9];
  const float* ln1_b  = (const float*)d_in[10];
  const float* ln2_g  = (const float*)d_in[11];
  const float* ln2_b  = (const float*)d_in[12];
  const int*   pos    = (const int*)d_in[13];

  float* hres = (float*)d_out;
  const size_t rows = (size_t)B_ * S_;  // 4096

  unsigned short* wQ    = (unsigned short*)d_ws;          // [L][3072][1024]
  unsigned short* wP    = wQ  + (size_t)2 * 3072 * 1024;  // [L][1024][1024]
  unsigned short* wF1   = wP  + (size_t)2 * 1024 * 1024;  // [L][4096][1024]
  unsigned short* wF2   = wF1 + (size_t)2 * 4096 * 1024;  // [L][1024][4096]
  unsigned short* xbf   = wF2 + (size_t)2 * 1024 * 4096;  // [4096][1024]
  unsigned short* qkvbf = xbf + rows * H_;                // [4096][3072]
  unsigned short* midbf = qkvbf + rows * 3 * H_;          // [4096][4096]
  unsigned short* aoutbf= midbf + rows * MLPH_;           // [4096][1024]

  hipMemcpyAsync(hres, hs, rows * H_ * sizeof(float), hipMemcpyDeviceToDevice, stream);

  for (int l = 0; l < 2; l++) {
    wconv<<<dim3(96, 32), 256, 0, stream>>>(attn_w + (size_t)l * 1024 * 3072,
                                            wQ + (size_t)l * 3072 * 1024, 1024, 3072);
    wconv<<<dim3(32, 32), 256, 0, stream>>>(proj_w + (size_t)l * 1024 * 1024,
                                            wP + (size_t)l * 1024 * 1024, 1024, 1024);
    wconv<<<dim3(128, 32), 256, 0, stream>>>(fc_w + (size_t)l * 1024 * 4096,
                                             wF1 + (size_t)l * 4096 * 1024, 1024, 4096);
    wconv<<<dim3(32, 128), 256, 0, stream>>>(fc2_w + (size_t)l * 4096 * 1024,
                                             wF2 + (size_t)l * 1024 * 4096, 4096, 1024);
  }

  for (int l = 0; l < 2; l++) {
    ln_kernel<<<rows, 256, 0, stream>>>(hres, ln1_g + l * H_, ln1_b + l * H_, xbf);
    gemm_mfma<0, 4><<<dim3(24, 32), 256, 0, stream>>>(
        xbf, wQ + (size_t)l * 3072 * 1024, attn_b + (size_t)l * 3072, nullptr,
        qkvbf, 4096, 3072, 1024);
    rope_bf<<<8192, 256, 0, stream>>>(qkvbf, pos);
    attn3<<<dim3(16, 16, 4), 256, 0, stream>>>(qkvbf, aoutbf);
    gemm_mfma<2, 2><<<dim3(16, 32), 256, 0, stream>>>(
        aoutbf, wP + (size_t)l * 1024 * 1024, proj_b + (size_t)l * 1024, hres,
        hres, 4096, 1024, 1024);
    ln_kernel<<<rows, 256, 0, stream>>>(hres, ln2_g + l * H_, ln2_b + l * H_, xbf);
    gemm_mfma<1, 4><<<dim3(32, 32), 256, 0, stream>>>(
        xbf, wF1 + (size_t)l * 4096 * 1024, fc_b + (size_t)l * 4096, nullptr,
        midbf, 4096, 4096, 1024);
    gemm_mfma<2, 2><<<dim3(16, 32), 256, 0, stream>>>(
        midbf, wF2 + (size_t)l * 1024 * 4096, fc2_b + (size_t)l * 1024, hres,
        hres, 4096, 1024, 4096);
  }
}

// Round 6
// 478.729 us; speedup vs baseline: 19.7731x; 1.1807x over previous
//
#include <hip/hip_runtime.h>

#define B_ 4
#define S_ 1024
#define H_ 1024
#define NH_ 16
#define DK_ 64
#define MLPH_ 4096
#define EPS_ 1e-5f

typedef __attribute__((ext_vector_type(8))) short short8_t;
typedef __attribute__((ext_vector_type(8))) unsigned short ushort8_t;
typedef __attribute__((ext_vector_type(4))) float f32x4;

__device__ __forceinline__ unsigned short f2bf(float f) {
  unsigned int u = __float_as_uint(f);
  u = u + 0x7fffu + ((u >> 16) & 1u);  // RNE
  return (unsigned short)(u >> 16);
}
__device__ __forceinline__ float bf2f(unsigned short b) {
  return __uint_as_float(((unsigned int)b) << 16);
}

__device__ __forceinline__ void gload16(const void* g, void* l) {
  typedef const __attribute__((address_space(1))) unsigned int GU;
  typedef __attribute__((address_space(3))) unsigned int LU;
  __builtin_amdgcn_global_load_lds((GU*)(size_t)g, (LU*)(unsigned int)(size_t)l, 16, 0, 0);
}

// gelu_tanh via sigmoid identity: 0.5x(1+tanh(u)) = x*sigma(2u). Overflow-safe.
__device__ __forceinline__ float gelu_tanh(float x) {
  float y = 1.5957691216057308f * (x + 0.044715f * x * x * x);  // 2*0.79788456*(...)
  return x / (1.0f + __expf(-y));
}

// ---------------- weight fp32 [K,N] -> bf16 [N,K] transpose ----------------
__global__ __launch_bounds__(256) void wconv(const float* __restrict__ src,
                                             unsigned short* __restrict__ dst,
                                             int K, int N) {
  __shared__ float t[32][33];
  int n0 = blockIdx.x * 32, k0 = blockIdx.y * 32;
  int tid = threadIdx.x;
  int r = tid >> 3, c = (tid & 7) * 4;
  const float* s = src + (size_t)(k0 + r) * N + n0 + c;
  float4 v = *(const float4*)s;
  t[r][c] = v.x; t[r][c + 1] = v.y; t[r][c + 2] = v.z; t[r][c + 3] = v.w;
  __syncthreads();
  ushort4 o;
  o.x = f2bf(t[c + 0][r]); o.y = f2bf(t[c + 1][r]);
  o.z = f2bf(t[c + 2][r]); o.w = f2bf(t[c + 3][r]);
  *(ushort4*)(dst + (size_t)(n0 + r) * K + k0 + c) = o;
}

// ---------------- LayerNorm -> bf16 out ----------------
__global__ __launch_bounds__(256) void ln_kernel(const float* __restrict__ x,
                                                 const float* __restrict__ g,
                                                 const float* __restrict__ b,
                                                 unsigned short* __restrict__ y) {
  int row = blockIdx.x, tid = threadIdx.x;
  const float* xp = x + (size_t)row * H_;
  float4 v = *((const float4*)xp + tid);
  float s  = v.x + v.y + v.z + v.w;
  float s2 = v.x * v.x + v.y * v.y + v.z * v.z + v.w * v.w;
  #pragma unroll
  for (int o = 1; o < 64; o <<= 1) {
    s  += __shfl_xor(s, o, 64);
    s2 += __shfl_xor(s2, o, 64);
  }
  __shared__ float r1[4], r2[4];
  if ((tid & 63) == 0) { r1[tid >> 6] = s; r2[tid >> 6] = s2; }
  __syncthreads();
  s  = r1[0] + r1[1] + r1[2] + r1[3];
  s2 = r2[0] + r2[1] + r2[2] + r2[3];
  float mean = s * (1.0f / H_);
  float var  = s2 * (1.0f / H_) - mean * mean;
  float inv  = rsqrtf(var + EPS_);
  float4 gv = *((const float4*)g + tid);
  float4 bv = *((const float4*)b + tid);
  ushort4 o;
  o.x = f2bf((v.x - mean) * inv * gv.x + bv.x);
  o.y = f2bf((v.y - mean) * inv * gv.y + bv.y);
  o.z = f2bf((v.z - mean) * inv * gv.z + bv.z);
  o.w = f2bf((v.w - mean) * inv * gv.w + bv.w);
  *(ushort4*)(y + (size_t)row * H_ + tid * 4) = o;
}

// ---------------- RoPE in-place on qkv bf16 [B,S,3H] ----------------
__global__ __launch_bounds__(256) void rope_bf(unsigned short* qkv, const int* __restrict__ pos) {
  int idx = blockIdx.x * 256 + threadIdx.x;  // over B*S*NH*32
  int d = idx & 31;
  int hh = (idx >> 5) & 15;
  int s = (idx >> 9) & 1023;
  int b = idx >> 19;
  size_t base = ((size_t)(b * S_ + s)) * 3072 + hh * 64;
  float inv = __expf(-9.210340371976184f * ((float)d * 0.03125f));  // 10000^(-d/32)
  float th = (float)pos[s] * inv;
  float cs = cosf(th), sn = sinf(th);
  unsigned short* qp = qkv + base;
  unsigned short* kp = qkv + base + 1024;
  float q0 = bf2f(qp[d]), q1 = bf2f(qp[d + 32]);
  float k0 = bf2f(kp[d]), k1 = bf2f(kp[d + 32]);
  qp[d]      = f2bf(q0 * cs - q1 * sn);
  qp[d + 32] = f2bf(q1 * cs + q0 * sn);
  kp[d]      = f2bf(k0 * cs - k1 * sn);
  kp[d + 32] = f2bf(k1 * cs + k0 * sn);
}

// ---------------- bf16 MFMA GEMM: 128xBN tile, BK=64, 4 waves, 2-phase dbuf ----------------
// A:[M,K] bf16 row-major; Bt:[N,K] bf16 row-major (W^T).
// T3 minimum-2-phase: STAGE(t+1) issued BEFORE compute(t); one vmcnt(0)+barrier per tile.
// LDS rows 128B, slot-swizzled via pre-swizzled global source + matching read XOR.
// MODE 0: bf16 = A*W+bias; MODE 1: bf16 = gelu(...); MODE 2: f32 = resid+...
template <int MODE, int NT>
__global__ __launch_bounds__(256) void gemm_mfma(
    const unsigned short* __restrict__ A, const unsigned short* __restrict__ Bt,
    const float* __restrict__ bias, const float* __restrict__ resid,
    void* __restrict__ outp, int M, int N, int K) {
  constexpr int BN = NT * 32;
  constexpr int CB = BN / 32;  // B chunks (8 rows) per wave
  __shared__ __align__(16) unsigned short As[2][128 * 64];
  __shared__ __align__(16) unsigned short Bs[2][BN * 64];
  int tid = threadIdx.x;
  int w = tid >> 6, lane = tid & 63;
  int m0 = blockIdx.y * 128, n0 = blockIdx.x * BN;
  int wr = w >> 1, wc = w & 1;
  int fr = lane & 15, kg = lane >> 4;
  f32x4 acc[4][NT];
  #pragma unroll
  for (int m = 0; m < 4; m++)
    #pragma unroll
    for (int n = 0; n < NT; n++) {
      acc[m][n][0] = 0.f; acc[m][n][1] = 0.f; acc[m][n][2] = 0.f; acc[m][n][3] = 0.f;
    }
  int srow = lane >> 3;
  int scol = ((lane & 7) ^ srow) * 8;  // pre-swizzled global source
  const unsigned short* Ap = A  + (size_t)(m0 + w * 32 + srow) * K + scol;
  const unsigned short* Bp = Bt + (size_t)(n0 + w * (8 * CB) + srow) * K + scol;
  int sx = (fr & 7);  // read-side swizzle key
  int nk = K >> 6;
  // prologue: stage tile 0 -> buf 0
  {
    char* AsB = (char*)As[0] + w * 4096;
    char* BsB = (char*)Bs[0] + w * CB * 1024;
    #pragma unroll
    for (int i = 0; i < 4; i++) gload16(Ap + (size_t)i * 8 * K, AsB + i * 1024);
    #pragma unroll
    for (int i = 0; i < CB; i++) gload16(Bp + (size_t)i * 8 * K, BsB + i * 1024);
  }
  __syncthreads();
  for (int t = 0; t < nk; t++) {
    int cur = t & 1;
    // issue next tile's staging loads (latency hides under this tile's compute)
    if (t + 1 < nk) {
      const unsigned short* Ap2 = Ap + (size_t)(t + 1) * 64;
      const unsigned short* Bp2 = Bp + (size_t)(t + 1) * 64;
      char* AsB = (char*)As[cur ^ 1] + w * 4096;
      char* BsB = (char*)Bs[cur ^ 1] + w * CB * 1024;
      #pragma unroll
      for (int i = 0; i < 4; i++) gload16(Ap2 + (size_t)i * 8 * K, AsB + i * 1024);
      #pragma unroll
      for (int i = 0; i < CB; i++) gload16(Bp2 + (size_t)i * 8 * K, BsB + i * 1024);
    }
    #pragma unroll
    for (int kk = 0; kk < 2; kk++) {
      int slot = ((kk * 4 + kg) ^ sx) << 4;
      short8_t af[4], bfr[NT];
      #pragma unroll
      for (int m = 0; m < 4; m++)
        af[m] = *(const short8_t*)((char*)As[cur] + (wr * 64 + m * 16 + fr) * 128 + slot);
      #pragma unroll
      for (int n = 0; n < NT; n++)
        bfr[n] = *(const short8_t*)((char*)Bs[cur] + (wc * (NT * 16) + n * 16 + fr) * 128 + slot);
      #pragma unroll
      for (int m = 0; m < 4; m++)
        #pragma unroll
        for (int n = 0; n < NT; n++)
          acc[m][n] = __builtin_amdgcn_mfma_f32_16x16x32_bf16(af[m], bfr[n], acc[m][n], 0, 0, 0);
    }
    __syncthreads();  // implicit vmcnt(0)+lgkmcnt(0) drain: next buffer ready, cur reusable
  }
  #pragma unroll
  for (int n = 0; n < NT; n++) {
    int col = n0 + wc * (NT * 16) + n * 16 + fr;
    float bv = bias[col];
    #pragma unroll
    for (int m = 0; m < 4; m++) {
      int row = m0 + wr * 64 + m * 16 + kg * 4;
      #pragma unroll
      for (int r = 0; r < 4; r++) {
        float v = acc[m][n][r] + bv;
        size_t idx = (size_t)(row + r) * N + col;
        if (MODE == 2)      ((float*)outp)[idx] = resid[idx] + v;
        else if (MODE == 1) ((unsigned short*)outp)[idx] = f2bf(gelu_tanh(v));
        else                ((unsigned short*)outp)[idx] = f2bf(v);
      }
    }
  }
}

// ---------------- MFMA flash attention: 4 waves x 16 q-rows, KVBLK=64 ----------------
// Double-buffered reg-staged K/V (async-STAGE), defer-max softmax,
// lane-local l partial reduced once at end. One barrier per kv-tile.
__global__ __launch_bounds__(256) void attn3(const unsigned short* __restrict__ qkv,
                                             unsigned short* __restrict__ aout) {
  __shared__ __align__(16) unsigned short Ks[2][64 * 64];   // [kv][d], swizzled
  __shared__ __align__(16) unsigned short Vt[2][64 * 64];   // [d][kv], swizzled
  __shared__ __align__(16) unsigned short Ps[4][16 * 64];   // per-wave P, swizzled
  int tid = threadIdx.x;
  int w = tid >> 6, lane = tid & 63;
  int fr = lane & 15, kg = lane >> 4;
  int qt = (int)gridDim.x - 1 - (int)blockIdx.x;  // heavy tiles first
  int q0 = qt * 64;
  int head = blockIdx.y, b = blockIdx.z;
  const unsigned short* base = qkv + ((size_t)b * S_) * 3072 + head * 64;

  const unsigned short* qp = base + (size_t)(q0 + w * 16 + fr) * 3072 + kg * 8;
  short8_t qa0 = *(const short8_t*)qp;
  short8_t qa1 = *(const short8_t*)(qp + 32);

  f32x4 acc[4];    // O accumulator: [n dk-tile][r]
  float mrun[4], lrun[4];
  #pragma unroll
  for (int n = 0; n < 4; n++) { acc[n][0] = 0.f; acc[n][1] = 0.f; acc[n][2] = 0.f; acc[n][3] = 0.f; }
  #pragma unroll
  for (int r = 0; r < 4; r++) { mrun[r] = -3.0e38f; lrun[r] = 0.f; }

  int skv = lane;       // staging: kv row
  int sd0 = w * 16;     // staging: dk offset

  // prologue: load tile 0 into regs
  const unsigned short* kp0 = base + 1024 + (size_t)skv * 3072 + sd0;
  short8_t ka = *(const short8_t*)kp0;
  short8_t kb = *(const short8_t*)(kp0 + 8);
  short8_t va = *(const short8_t*)(kp0 + 1024);
  short8_t vb = *(const short8_t*)(kp0 + 1032);

  for (int t = 0; t <= qt; t++) {
    int cur = t & 1;
    // ---- write staged regs -> LDS[cur] ----
    {
      unsigned kbyte = skv * 128 + sd0 * 2;
      unsigned ksw = (skv & 7) << 4;
      *(short8_t*)((char*)Ks[cur] + (kbyte ^ ksw)) = ka;
      *(short8_t*)((char*)Ks[cur] + ((kbyte + 16) ^ ksw)) = kb;
      #pragma unroll
      for (int j = 0; j < 8; j++) {
        int d0 = sd0 + j, d1 = sd0 + 8 + j;
        *(unsigned short*)((char*)Vt[cur] + ((d0 * 128 + skv * 2) ^ ((d0 & 7) << 4))) = (unsigned short)va[j];
        *(unsigned short*)((char*)Vt[cur] + ((d1 * 128 + skv * 2) ^ ((d1 & 7) << 4))) = (unsigned short)vb[j];
      }
    }
    // ---- issue next tile's global loads (latency hides under compute) ----
    if (t < qt) {
      const unsigned short* kp = base + 1024 + (size_t)((t + 1) * 64 + skv) * 3072 + sd0;
      ka = *(const short8_t*)kp;
      kb = *(const short8_t*)(kp + 8);
      va = *(const short8_t*)(kp + 1024);
      vb = *(const short8_t*)(kp + 1032);
    }
    __syncthreads();
    // ---- QK^T: S[16 x 64] per wave ----
    f32x4 s[4];
    #pragma unroll
    for (int n = 0; n < 4; n++) {
      int kvrow = n * 16 + fr;
      unsigned sw = (kvrow & 7) << 4;
      short8_t b0 = *(const short8_t*)((char*)Ks[cur] + ((kvrow * 128 + kg * 16) ^ sw));
      short8_t b1 = *(const short8_t*)((char*)Ks[cur] + ((kvrow * 128 + 64 + kg * 16) ^ sw));
      f32x4 z; z[0] = 0.f; z[1] = 0.f; z[2] = 0.f; z[3] = 0.f;
      z = __builtin_amdgcn_mfma_f32_16x16x32_bf16(qa0, b0, z, 0, 0, 0);
      z = __builtin_amdgcn_mfma_f32_16x16x32_bf16(qa1, b1, z, 0, 0, 0);
      s[n] = z;
    }
    // ---- softmax: defer-max + lane-local l partial ----
    bool diag = (t == qt);
    float p[4][4], pmax[4];
    #pragma unroll
    for (int r = 0; r < 4; r++) {
      int qrow = w * 16 + kg * 4 + r;
      float rm = -3.0e38f;
      #pragma unroll
      for (int n = 0; n < 4; n++) {
        float sv = s[n][r] * 0.125f;
        if (diag && (n * 16 + fr > qrow)) sv = -3.0e38f;
        s[n][r] = sv;
        rm = fmaxf(rm, sv);
      }
      pmax[r] = rm;
    }
    bool need = (pmax[0] > mrun[0] + 8.f) | (pmax[1] > mrun[1] + 8.f) |
                (pmax[2] > mrun[2] + 8.f) | (pmax[3] > mrun[3] + 8.f);
    if (__any(need)) {
      #pragma unroll
      for (int r = 0; r < 4; r++) {
        float rm = pmax[r];
        rm = fmaxf(rm, __shfl_xor(rm, 1, 64));
        rm = fmaxf(rm, __shfl_xor(rm, 2, 64));
        rm = fmaxf(rm, __shfl_xor(rm, 4, 64));
        rm = fmaxf(rm, __shfl_xor(rm, 8, 64));
        float mn = fmaxf(mrun[r], rm);
        float sc = __expf(mrun[r] - mn);
        mrun[r] = mn;
        lrun[r] *= sc;
        #pragma unroll
        for (int n = 0; n < 4; n++) acc[n][r] *= sc;
      }
    }
    #pragma unroll
    for (int r = 0; r < 4; r++) {
      float ls = 0.f;
      #pragma unroll
      for (int n = 0; n < 4; n++) {
        float e = __expf(s[n][r] - mrun[r]);
        p[n][r] = e;
        ls += e;
      }
      lrun[r] += ls;  // per-lane partial; reduced once at end
    }
    // ---- P -> per-wave LDS (bf16, A-frag layout, swizzled) ----
    #pragma unroll
    for (int n = 0; n < 4; n++)
      #pragma unroll
      for (int r = 0; r < 4; r++) {
        int row = kg * 4 + r, col = n * 16 + fr;
        *(unsigned short*)((char*)Ps[w] + ((row * 128 + col * 2) ^ ((row & 7) << 4))) = f2bf(p[n][r]);
      }
    asm volatile("s_waitcnt lgkmcnt(0)" ::: "memory");
    // ---- PV ----
    unsigned psw = (fr & 7) << 4;
    short8_t pa0 = *(const short8_t*)((char*)Ps[w] + ((fr * 128 + kg * 16) ^ psw));
    short8_t pa1 = *(const short8_t*)((char*)Ps[w] + ((fr * 128 + 64 + kg * 16) ^ psw));
    #pragma unroll
    for (int n = 0; n < 4; n++) {
      int d = n * 16 + fr;
      unsigned sw = (d & 7) << 4;
      short8_t v0 = *(const short8_t*)((char*)Vt[cur] + ((d * 128 + kg * 16) ^ sw));
      short8_t v1 = *(const short8_t*)((char*)Vt[cur] + ((d * 128 + 64 + kg * 16) ^ sw));
      acc[n] = __builtin_amdgcn_mfma_f32_16x16x32_bf16(pa0, v0, acc[n], 0, 0, 0);
      acc[n] = __builtin_amdgcn_mfma_f32_16x16x32_bf16(pa1, v1, acc[n], 0, 0, 0);
    }
  }
  // ---- epilogue: reduce l across the 16-lane row group, normalize, store ----
  #pragma unroll
  for (int r = 0; r < 4; r++) {
    float ls = lrun[r];
    ls += __shfl_xor(ls, 1, 64);
    ls += __shfl_xor(ls, 2, 64);
    ls += __shfl_xor(ls, 4, 64);
    ls += __shfl_xor(ls, 8, 64);
    float inv = 1.0f / ls;
    size_t row = (size_t)b * S_ + q0 + w * 16 + kg * 4 + r;
    unsigned short* op = aout + row * H_ + head * 64 + fr;
    #pragma unroll
    for (int n = 0; n < 4; n++) op[n * 16] = f2bf(acc[n][r] * inv);
  }
}

extern "C" void kernel_launch(void* const* d_in, const int* in_sizes, int n_in,
                              void* d_out, int out_size, void* d_ws, size_t ws_size,
                              hipStream_t stream) {
  const float* hs     = (const float*)d_in[0];
  const float* attn_w = (const float*)d_in[1];
  const float* attn_b = (const float*)d_in[2];
  const float* proj_w = (const float*)d_in[3];
  const float* proj_b = (const float*)d_in[4];
  const float* fc_w   = (const float*)d_in[5];
  const float* fc_b   = (const float*)d_in[6];
  const float* fc2_w  = (const float*)d_in[7];
  const float* fc2_b  = (const float*)d_in[8];
  const float* ln1_g  = (const float*)d_in[9];
  const float* ln1_b  = (const float*)d_in[10];
  const float* ln2_g  = (const float*)d_in[11];
  const float* ln2_b  = (const float*)d_in[12];
  const int*   pos    = (const int*)d_in[13];

  float* hres = (float*)d_out;
  const size_t rows = (size_t)B_ * S_;  // 4096

  unsigned short* wQ    = (unsigned short*)d_ws;          // [L][3072][1024]
  unsigned short* wP    = wQ  + (size_t)2 * 3072 * 1024;  // [L][1024][1024]
  unsigned short* wF1   = wP  + (size_t)2 * 1024 * 1024;  // [L][4096][1024]
  unsigned short* wF2   = wF1 + (size_t)2 * 4096 * 1024;  // [L][1024][4096]
  unsigned short* xbf   = wF2 + (size_t)2 * 1024 * 4096;  // [4096][1024]
  unsigned short* qkvbf = xbf + rows * H_;                // [4096][3072]
  unsigned short* midbf = qkvbf + rows * 3 * H_;          // [4096][4096]
  unsigned short* aoutbf= midbf + rows * MLPH_;           // [4096][1024]

  hipMemcpyAsync(hres, hs, rows * H_ * sizeof(float), hipMemcpyDeviceToDevice, stream);

  for (int l = 0; l < 2; l++) {
    wconv<<<dim3(96, 32), 256, 0, stream>>>(attn_w + (size_t)l * 1024 * 3072,
                                            wQ + (size_t)l * 3072 * 1024, 1024, 3072);
    wconv<<<dim3(32, 32), 256, 0, stream>>>(proj_w + (size_t)l * 1024 * 1024,
                                            wP + (size_t)l * 1024 * 1024, 1024, 1024);
    wconv<<<dim3(128, 32), 256, 0, stream>>>(fc_w + (size_t)l * 1024 * 4096,
                                             wF1 + (size_t)l * 4096 * 1024, 1024, 4096);
    wconv<<<dim3(32, 128), 256, 0, stream>>>(fc2_w + (size_t)l * 4096 * 1024,
                                             wF2 + (size_t)l * 1024 * 4096, 4096, 1024);
  }

  for (int l = 0; l < 2; l++) {
    ln_kernel<<<rows, 256, 0, stream>>>(hres, ln1_g + l * H_, ln1_b + l * H_, xbf);
    gemm_mfma<0, 4><<<dim3(24, 32), 256, 0, stream>>>(
        xbf, wQ + (size_t)l * 3072 * 1024, attn_b + (size_t)l * 3072, nullptr,
        qkvbf, 4096, 3072, 1024);
    rope_bf<<<8192, 256, 0, stream>>>(qkvbf, pos);
    attn3<<<dim3(16, 16, 4), 256, 0, stream>>>(qkvbf, aoutbf);
    gemm_mfma<2, 2><<<dim3(16, 32), 256, 0, stream>>>(
        aoutbf, wP + (size_t)l * 1024 * 1024, proj_b + (size_t)l * 1024, hres,
        hres, 4096, 1024, 1024);
    ln_kernel<<<rows, 256, 0, stream>>>(hres, ln2_g + l * H_, ln2_b + l * H_, xbf);
    gemm_mfma<1, 4><<<dim3(32, 32), 256, 0, stream>>>(
        xbf, wF1 + (size_t)l * 4096 * 1024, fc_b + (size_t)l * 4096, nullptr,
        midbf, 4096, 4096, 1024);
    gemm_mfma<2, 2><<<dim3(16, 32), 256, 0, stream>>>(
        midbf, wF2 + (size_t)l * 1024 * 4096, fc2_b + (size_t)l * 1024, hres,
        hres, 4096, 1024, 4096);
  }
}